// Round 2
// baseline (317.248 us; speedup 1.0000x reference)
//
#include <hip/hip_runtime.h>
#include <hip/hip_bf16.h>
#include <stdint.h>

#define NH 16
#define SEQ 2048
#define DMODEL 1024
#define DK 64
#define BATCH 4
#define M_TOT 8192  // BATCH * SEQ

#define LOG2E 1.44269504088896f
#define QSCALE (0.125f * LOG2E)   // 1/sqrt(DK) * log2(e), folded into Q

typedef short v8bf __attribute__((ext_vector_type(8)));   // 8 bf16 bit-patterns
typedef float f32x4 __attribute__((ext_vector_type(4)));

// Software RNE f32->bf16 (proven pack order; R0's v_cvt_pk_bf16_f32 graft had
// wrong pack semantics -> O(1) errors in oproj/V-store; do NOT re-graft
// without an isolated semantics probe).
__device__ __forceinline__ unsigned short f2bf(float f) {
  union { float f; unsigned u; } v; v.f = f;
  return (unsigned short)((v.u + 0x7fffu + ((v.u >> 16) & 1u)) >> 16);
}

__device__ __forceinline__ unsigned pack_bf2(float a, float b) {
  return (unsigned)f2bf(a) | ((unsigned)f2bf(b) << 16);
}

// async global->LDS, 16B per lane; LDS dest = wave-uniform base + lane*16
__device__ __forceinline__ void async_load16(const void* g, void* l) {
  __builtin_amdgcn_global_load_lds(
      (const __attribute__((address_space(1))) unsigned int*)(uintptr_t)g,
      (__attribute__((address_space(3))) unsigned int*)(unsigned)(uintptr_t)l,
      16, 0, 0);
}

// ---------------------------------------------------------------------------
// fp32 -> bf16 bulk conversion: query/key/value + Wq/Wk/Wv/Wo.
// ---------------------------------------------------------------------------
__global__ __launch_bounds__(256)
void cvt_kernel(const float* __restrict__ q, const float* __restrict__ k,
                const float* __restrict__ v,
                const float* __restrict__ wq, const float* __restrict__ wk,
                const float* __restrict__ wv, const float* __restrict__ wo,
                unsigned short* __restrict__ oq, unsigned short* __restrict__ ok,
                unsigned short* __restrict__ ov,
                unsigned short* __restrict__ owq, unsigned short* __restrict__ owk,
                unsigned short* __restrict__ owv, unsigned short* __restrict__ owo)
{
  const size_t XN = (size_t)M_TOT * DMODEL;
  const size_t WN = (size_t)DMODEL * DMODEL;
  const float* s; unsigned short* d; size_t n;
  switch (blockIdx.y) {
    case 0: s = q;  d = oq;  n = XN; break;
    case 1: s = k;  d = ok;  n = XN; break;
    case 2: s = v;  d = ov;  n = XN; break;
    case 3: s = wq; d = owq; n = WN; break;
    case 4: s = wk; d = owk; n = WN; break;
    case 5: s = wv; d = owv; n = WN; break;
    default: s = wo; d = owo; n = WN; break;
  }
  for (size_t i = ((size_t)blockIdx.x * 256 + threadIdx.x) * 8; i < n;
       i += (size_t)gridDim.x * 256 * 8) {
    float4 a = *(const float4*)(s + i);
    float4 b = *(const float4*)(s + i + 4);
    uint4 p = { pack_bf2(a.x, a.y), pack_bf2(a.z, a.w),
                pack_bf2(b.x, b.y), pack_bf2(b.z, b.w) };
    *(uint4*)(d + i) = p;
  }
}

// ---------------------------------------------------------------------------
// bf16 projection GEMM (m97-style): Out = (X @ W^T + b) * scale
// 128x128 tile, BK=64, global_load_lds staging, XOR-swizzled LDS cols.
// Q/K -> [B,H,S,DK] bf16;  V -> [B,H,DK,SEQ] bf16 (transposed).
// ---------------------------------------------------------------------------
__global__ __launch_bounds__(256, 2)
void proj_bf16_kernel(const unsigned short* __restrict__ Xq,
                      const unsigned short* __restrict__ Xk,
                      const unsigned short* __restrict__ Xv,
                      const unsigned short* __restrict__ Wqc,
                      const unsigned short* __restrict__ Wkc,
                      const unsigned short* __restrict__ Wvc,
                      const float* __restrict__ bq, const float* __restrict__ bk,
                      const float* __restrict__ bv,
                      unsigned short* __restrict__ Qp, unsigned short* __restrict__ Kp,
                      unsigned short* __restrict__ Vp)
{
  const int z = blockIdx.z;
  const unsigned short* A = (z == 0) ? Xq : (z == 1) ? Xk : Xv;
  const unsigned short* W = (z == 0) ? Wqc : (z == 1) ? Wkc : Wvc;
  const float* bias = (z == 0) ? bq : (z == 1) ? bk : bv;
  unsigned short* Out = (z == 0) ? Qp : (z == 1) ? Kp : Vp;
  const float scale = (z == 0) ? QSCALE : 1.0f;

  // unpadded [128][64]; LDS[row][u] = global[row][u ^ (row&7)] (16B units)
  __shared__ unsigned short As[128 * 64];
  __shared__ unsigned short Bs[128 * 64];

  const int tid  = threadIdx.x;
  const int m0   = blockIdx.x * 128;
  const int n0   = blockIdx.y * 128;
  const int lane = tid & 63;
  const int wave = tid >> 6;
  const int quad = lane >> 4;
  const int l16  = lane & 15;
  const int wm   = (wave >> 1) * 64;
  const int wn   = (wave & 1) * 64;
  const int lrow = lane >> 3;     // 0..7
  const int lcol = lane & 7;      // 16B unit

  f32x4 acc[4][4];
#pragma unroll
  for (int i = 0; i < 4; ++i)
#pragma unroll
    for (int j = 0; j < 4; ++j) acc[i][j] = (f32x4){0.f, 0.f, 0.f, 0.f};

  for (int k0 = 0; k0 < DMODEL; k0 += 64) {
#pragma unroll
    for (int i = 0; i < 4; ++i) {
      int row = wave * 32 + i * 8 + lrow;
      int gc = (lcol ^ (row & 7)) * 8;    // element offset within BK
      async_load16(A + (size_t)(m0 + row) * DMODEL + k0 + gc, &As[(wave * 32 + i * 8) * 64]);
      async_load16(W + (size_t)(n0 + row) * DMODEL + k0 + gc, &Bs[(wave * 32 + i * 8) * 64]);
    }
    __syncthreads();

#pragma unroll
    for (int ks = 0; ks < 2; ++ks) {
      v8bf af[4], bf[4];
#pragma unroll
      for (int i = 0; i < 4; ++i)
        af[i] = *(const v8bf*)&As[(wm + i * 16 + l16) * 64 + ((ks * 4 + quad) ^ (l16 & 7)) * 8];
#pragma unroll
      for (int j = 0; j < 4; ++j)
        bf[j] = *(const v8bf*)&Bs[(wn + j * 16 + l16) * 64 + ((ks * 4 + quad) ^ (l16 & 7)) * 8];
#pragma unroll
      for (int i = 0; i < 4; ++i)
#pragma unroll
        for (int j = 0; j < 4; ++j)
          acc[i][j] = __builtin_amdgcn_mfma_f32_16x16x32_bf16(af[i], bf[j], acc[i][j], 0, 0, 0);
    }
    __syncthreads();
  }

  if (z < 2) {
    // scatter to [B, H, S, DK] bf16
#pragma unroll
    for (int j = 0; j < 4; ++j) {
      int colg = n0 + wn + j * 16 + l16;
      float bj = bias[colg];
      int h = colg >> 6, d = colg & 63;
#pragma unroll
      for (int i = 0; i < 4; ++i) {
#pragma unroll
        for (int reg = 0; reg < 4; ++reg) {
          int mrow = m0 + wm + i * 16 + quad * 4 + reg;
          int bb = mrow >> 11, ss = mrow & 2047;
          float val = (acc[i][j][reg] + bj) * scale;
          Out[(((size_t)bb * NH + h) * SEQ + ss) * DK + d] = f2bf(val);
        }
      }
    }
  } else {
    // V transposed: [B, H, DK, SEQ]; 4 C-regs = 4 consecutive seq rows
#pragma unroll
    for (int j = 0; j < 4; ++j) {
      int colg = n0 + wn + j * 16 + l16;
      float bj = bias[colg];
      int h = colg >> 6, d = colg & 63;
#pragma unroll
      for (int i = 0; i < 4; ++i) {
        int mrow = m0 + wm + i * 16 + quad * 4;     // 4-aligned
        int bb = mrow >> 11, ss = mrow & 2047;
        uint2 pk = { pack_bf2(acc[i][j][0] + bj, acc[i][j][1] + bj),
                     pack_bf2(acc[i][j][2] + bj, acc[i][j][3] + bj) };
        *(uint2*)(Out + (((size_t)bb * NH + h) * DK + d) * SEQ + ss) = pk;
      }
    }
  }
}

// ---------------------------------------------------------------------------
// Causal flash attention. Block = 128 q-rows x one (b,h). 4 waves; wave w owns
// 32 q-rows. KV chunks of 64, double-buffered LDS via global_load_lds.
// No-max softmax; denominator deferred to epilogue. LDS 40960 B -> 4 blk/CU.
//
// Load balance: hardware round-robin gives CU c blocks {c, c+256, c+512,
// c+768} -> y in {r, r+4, r+8, r+12}, r = c/64.  qt map is chosen so each
// stride-4 residue class has equal chunk totals:
//   r-class gets qt {15-r, 8+r, 7-r, r}:  (qt+1) sums = 34 for every r
//   -> 68 chunks per CU (was 104/96/40/32 with the old consecutive-pair map).
// ---------------------------------------------------------------------------
__global__ __launch_bounds__(256, 2)
void attn_kernel(const unsigned short* __restrict__ Qp,
                 const unsigned short* __restrict__ Kp,
                 const unsigned short* __restrict__ VTp,
                 unsigned short* __restrict__ Xout)
{
  const int y  = blockIdx.y;        // 0..15
  const int r  = y & 3, jj = y >> 2;
  const int qt = (jj == 0) ? (15 - r) : (jj == 1) ? (8 + r) : (jj == 2) ? (7 - r) : r;
  const int bh = blockIdx.x;        // 0..63
  const int b  = bh >> 4, h = bh & 15;

  const unsigned short* Qb = Qp  + ((size_t)bh * SEQ + qt * 128) * DK;
  const unsigned short* Kb = Kp  + (size_t)bh * SEQ * DK;
  const unsigned short* Vb = VTp + (size_t)bh * DK * SEQ;   // [DK][SEQ]

  __shared__ unsigned short Ks[2][64 * 64];   // [kv][d], xor-swizzled 16B cols
  __shared__ unsigned short VTs[2][64 * 64];  // [d][kv], xor-swizzled
  __shared__ unsigned short Ps[4][16 * 64];   // per-wave P, group-swizzled

  const int tid  = threadIdx.x;
  const int lane = tid & 63, wave = tid >> 6;
  const int quad = lane >> 4, l16 = lane & 15;
  const int row_lo = qt * 128 + wave * 32;    // this wave's first q row

  // Q fragments straight from global (A-layout: m=l16, k=quad*8+j)
  v8bf qf[2][2];
#pragma unroll
  for (int rf = 0; rf < 2; ++rf)
#pragma unroll
    for (int ks = 0; ks < 2; ++ks)
      qf[rf][ks] = *(const v8bf*)(Qb + (size_t)(wave * 32 + rf * 16 + l16) * DK + ks * 32 + quad * 8);

  float lp[2][4];                   // per-lane partial row sums (denominator)
  f32x4 o[2][4];
#pragma unroll
  for (int rf = 0; rf < 2; ++rf)
#pragma unroll
    for (int reg = 0; reg < 4; ++reg) lp[rf][reg] = 0.f;
#pragma unroll
  for (int rf = 0; rf < 2; ++rf)
#pragma unroll
    for (int df = 0; df < 4; ++df) o[rf][df] = (f32x4){0.f, 0.f, 0.f, 0.f};

  const int nchunk = 2 * (qt + 1);
  const int lrow = lane >> 3;       // 0..7
  const int lcol = lane & 7;        // physical 16B col within row

  // stage chunk 0 into buf 0
#pragma unroll
  for (int is = 0; is < 2; ++is) {
    int row = wave * 16 + is * 8 + lrow;
    int cK = ((lcol ^ (row & 7)) * 8);
    async_load16(Kb + (size_t)row * DK + cK, &Ks[0][(wave * 16 + is * 8) * 64]);
    async_load16(Vb + (size_t)row * SEQ + cK, &VTs[0][(wave * 16 + is * 8) * 64]);
  }
  __syncthreads();

  for (int c = 0; c < nchunk; ++c) {
    const int buf = c & 1;
    const int kb  = c * 64;

    if (c + 1 < nchunk) {
      const int kb2 = kb + 64;
#pragma unroll
      for (int is = 0; is < 2; ++is) {
        int row = wave * 16 + is * 8 + lrow;
        int cc = ((lcol ^ (row & 7)) * 8);
        async_load16(Kb + (size_t)(kb2 + row) * DK + cc, &Ks[buf ^ 1][(wave * 16 + is * 8) * 64]);
        async_load16(Vb + (size_t)row * SEQ + kb2 + cc, &VTs[buf ^ 1][(wave * 16 + is * 8) * 64]);
      }
    }

    if (kb <= row_lo + 31) {    // wave has unmasked work in this chunk
      // ---- S = Q K^T ----
      f32x4 s[2][4];
#pragma unroll
      for (int rf = 0; rf < 2; ++rf)
#pragma unroll
        for (int nf = 0; nf < 4; ++nf) s[rf][nf] = (f32x4){0.f, 0.f, 0.f, 0.f};
#pragma unroll
      for (int ks = 0; ks < 2; ++ks)
#pragma unroll
        for (int nf = 0; nf < 4; ++nf) {
          v8bf kf = *(const v8bf*)&Ks[buf][(nf * 16 + l16) * 64 + ((ks * 4 + quad) ^ (l16 & 7)) * 8];
          s[0][nf] = __builtin_amdgcn_mfma_f32_16x16x32_bf16(qf[0][ks], kf, s[0][nf], 0, 0, 0);
          s[1][nf] = __builtin_amdgcn_mfma_f32_16x16x32_bf16(qf[1][ks], kf, s[1][nf], 0, 0, 0);
        }

      // ---- causal mask (only on diagonal-touching chunks) ----
      if (kb + 63 > row_lo) {
#pragma unroll
        for (int rf = 0; rf < 2; ++rf)
#pragma unroll
          for (int nf = 0; nf < 4; ++nf) {
            int col = kb + nf * 16 + l16;
#pragma unroll
            for (int reg = 0; reg < 4; ++reg)
              if (col > row_lo + rf * 16 + quad * 4 + reg) s[rf][nf][reg] = -1e30f;
          }
      }

      // ---- exp2 (no max subtraction) + deferred denominator + PV ----
#pragma unroll
      for (int rf = 0; rf < 2; ++rf) {
#pragma unroll
        for (int nf = 0; nf < 4; ++nf)
#pragma unroll
          for (int reg = 0; reg < 4; ++reg)
            s[rf][nf][reg] = __builtin_amdgcn_exp2f(s[rf][nf][reg]);
#pragma unroll
        for (int reg = 0; reg < 4; ++reg)
          lp[rf][reg] += (s[rf][0][reg] + s[rf][1][reg]) + (s[rf][2][reg] + s[rf][3][reg]);

        // P: C-layout -> per-wave LDS, swizzled: addr = row*64 + ((g ^ quad*2)*8 + off)
#pragma unroll
        for (int nf = 0; nf < 4; ++nf)
#pragma unroll
          for (int reg = 0; reg < 4; ++reg)
            Ps[wave][(quad * 4 + reg) * 64 +
                     (((nf * 2 + (l16 >> 3)) ^ (quad * 2)) * 8) + (l16 & 7)] =
                f2bf(s[rf][nf][reg]);

        // A-frag read: row=l16, k-group ks*4+quad, unswizzle with key (l16>>2)*2
#pragma unroll
        for (int ks = 0; ks < 2; ++ks) {
          v8bf pf = *(const v8bf*)&Ps[wave][l16 * 64 + (((ks * 4 + quad) ^ ((l16 >> 2) * 2)) * 8)];
#pragma unroll
          for (int df = 0; df < 4; ++df) {
            v8bf vf = *(const v8bf*)&VTs[buf][(df * 16 + l16) * 64 + ((ks * 4 + quad) ^ (l16 & 7)) * 8];
            o[rf][df] = __builtin_amdgcn_mfma_f32_16x16x32_bf16(pf, vf, o[rf][df], 0, 0, 0);
          }
        }
      }
    }
    __syncthreads();   // drains async loads (buf^1) + protects buf for c+2
  }

  // epilogue: one denominator reduction, then [B, S, H*DK] bf16
#pragma unroll
  for (int rf = 0; rf < 2; ++rf) {
#pragma unroll
    for (int off = 1; off < 16; off <<= 1)
#pragma unroll
      for (int reg = 0; reg < 4; ++reg) lp[rf][reg] += __shfl_xor(lp[rf][reg], off);
    float inv[4];
#pragma unroll
    for (int reg = 0; reg < 4; ++reg) inv[reg] = 1.0f / lp[rf][reg];
#pragma unroll
    for (int df = 0; df < 4; ++df)
#pragma unroll
      for (int reg = 0; reg < 4; ++reg) {
        int qrow = row_lo + rf * 16 + quad * 4 + reg;
        Xout[(size_t)(b * SEQ + qrow) * DMODEL + h * DK + df * 16 + l16] =
            f2bf(o[rf][df][reg] * inv[reg]);
      }
  }
}

// ---------------------------------------------------------------------------
// Output projection (bf16 GEMM, fp32 out): d_out = Xa @ Wo^T + bo
// ---------------------------------------------------------------------------
__global__ __launch_bounds__(256, 2)
void oproj_kernel(const unsigned short* __restrict__ Xa,
                  const unsigned short* __restrict__ Woc,
                  const float* __restrict__ bo,
                  float* __restrict__ Out)
{
  __shared__ unsigned short As[128 * 64];
  __shared__ unsigned short Bs[128 * 64];

  const int tid  = threadIdx.x;
  const int m0   = blockIdx.x * 128;
  const int n0   = blockIdx.y * 128;
  const int lane = tid & 63;
  const int wave = tid >> 6;
  const int quad = lane >> 4;
  const int l16  = lane & 15;
  const int wm   = (wave >> 1) * 64;
  const int wn   = (wave & 1) * 64;
  const int lrow = lane >> 3;
  const int lcol = lane & 7;

  f32x4 acc[4][4];
#pragma unroll
  for (int i = 0; i < 4; ++i)
#pragma unroll
    for (int j = 0; j < 4; ++j) acc[i][j] = (f32x4){0.f, 0.f, 0.f, 0.f};

  for (int k0 = 0; k0 < DMODEL; k0 += 64) {
#pragma unroll
    for (int i = 0; i < 4; ++i) {
      int row = wave * 32 + i * 8 + lrow;
      int gc = (lcol ^ (row & 7)) * 8;
      async_load16(Xa  + (size_t)(m0 + row) * DMODEL + k0 + gc, &As[(wave * 32 + i * 8) * 64]);
      async_load16(Woc + (size_t)(n0 + row) * DMODEL + k0 + gc, &Bs[(wave * 32 + i * 8) * 64]);
    }
    __syncthreads();

#pragma unroll
    for (int ks = 0; ks < 2; ++ks) {
      v8bf af[4], bf[4];
#pragma unroll
      for (int i = 0; i < 4; ++i)
        af[i] = *(const v8bf*)&As[(wm + i * 16 + l16) * 64 + ((ks * 4 + quad) ^ (l16 & 7)) * 8];
#pragma unroll
      for (int j = 0; j < 4; ++j)
        bf[j] = *(const v8bf*)&Bs[(wn + j * 16 + l16) * 64 + ((ks * 4 + quad) ^ (l16 & 7)) * 8];
#pragma unroll
      for (int i = 0; i < 4; ++i)
#pragma unroll
        for (int j = 0; j < 4; ++j)
          acc[i][j] = __builtin_amdgcn_mfma_f32_16x16x32_bf16(af[i], bf[j], acc[i][j], 0, 0, 0);
    }
    __syncthreads();
  }

#pragma unroll
  for (int j = 0; j < 4; ++j) {
    int colg = n0 + wn + j * 16 + l16;
    float bj = bo[colg];
#pragma unroll
    for (int i = 0; i < 4; ++i) {
#pragma unroll
      for (int reg = 0; reg < 4; ++reg) {
        int mrow = m0 + wm + i * 16 + quad * 4 + reg;
        Out[(size_t)mrow * DMODEL + colg] = acc[i][j][reg] + bj;
      }
    }
  }
}

extern "C" void kernel_launch(void* const* d_in, const int* in_sizes, int n_in,
                              void* d_out, int out_size, void* d_ws, size_t ws_size,
                              hipStream_t stream)
{
  const float* query = (const float*)d_in[0];
  const float* key   = (const float*)d_in[1];
  const float* value = (const float*)d_in[2];
  const float* Wq = (const float*)d_in[3];
  const float* bq = (const float*)d_in[4];
  const float* Wk = (const float*)d_in[5];
  const float* bk = (const float*)d_in[6];
  const float* Wv = (const float*)d_in[7];
  const float* bv = (const float*)d_in[8];
  const float* Wo = (const float*)d_in[9];
  const float* bo = (const float*)d_in[10];

  const size_t tsz = (size_t)M_TOT * DMODEL;   // elements per bf16 X-tensor
  const size_t wsz = (size_t)DMODEL * DMODEL;  // elements per bf16 W-tensor
  unsigned short* Qp  = (unsigned short*)d_ws;
  unsigned short* Kp  = Qp + tsz;
  unsigned short* Vp  = Kp + tsz;   // transposed per-head: [B,H,DK,SEQ]
  unsigned short* Xa  = Vp + tsz;
  unsigned short* Xqc = Xa + tsz;
  unsigned short* Xkc = Xqc + tsz;
  unsigned short* Xvc = Xkc + tsz;
  unsigned short* Wqc = Xvc + tsz;
  unsigned short* Wkc = Wqc + wsz;
  unsigned short* Wvc = Wkc + wsz;
  unsigned short* Woc = Wvc + wsz;

  cvt_kernel<<<dim3(1024, 7), 256, 0, stream>>>(query, key, value, Wq, Wk, Wv, Wo,
                                                Xqc, Xkc, Xvc, Wqc, Wkc, Wvc, Woc);
  proj_bf16_kernel<<<dim3(64, 8, 3), 256, 0, stream>>>(Xqc, Xkc, Xvc, Wqc, Wkc, Wvc,
                                                       bq, bk, bv, Qp, Kp, Vp);
  attn_kernel<<<dim3(64, 16), 256, 0, stream>>>(Qp, Kp, Vp, Xa);
  oproj_kernel<<<dim3(64, 8), 256, 0, stream>>>(Xa, Woc, bo, (float*)d_out);
}

// Round 3
// 311.622 us; speedup vs baseline: 1.0181x; 1.0181x over previous
//
#include <hip/hip_runtime.h>
#include <hip/hip_bf16.h>
#include <stdint.h>

#define NH 16
#define SEQ 2048
#define DMODEL 1024
#define DK 64
#define BATCH 4
#define M_TOT 8192  // BATCH * SEQ

#define LOG2E 1.44269504088896f
#define QSCALE (0.125f * LOG2E)   // 1/sqrt(DK) * log2(e), folded into Q

typedef short v8bf __attribute__((ext_vector_type(8)));   // 8 bf16 bit-patterns
typedef float f32x4 __attribute__((ext_vector_type(4)));

// f32->bf16 RNE via compiler intrinsics (compiler-guaranteed pack semantics;
// R1 lesson: raw `v_cvt_pk_bf16_f32` asm had wrong operand order -> O(1) errs).
__device__ __forceinline__ unsigned pack_bf2(float a, float b) {
  union { __hip_bfloat162 h; unsigned u; } v;
  v.h = __float22bfloat162_rn(make_float2(a, b));
  return v.u;
}

__device__ __forceinline__ unsigned short f2bf(float f) {
  union { __hip_bfloat16 h; unsigned short u; } v;
  v.h = __float2bfloat16(f);
  return v.u;
}

// async global->LDS, 16B per lane; LDS dest = wave-uniform base + lane*16
__device__ __forceinline__ void async_load16(const void* g, void* l) {
  __builtin_amdgcn_global_load_lds(
      (const __attribute__((address_space(1))) unsigned int*)(uintptr_t)g,
      (__attribute__((address_space(3))) unsigned int*)(unsigned)(uintptr_t)l,
      16, 0, 0);
}

// ---------------------------------------------------------------------------
// fp32 -> bf16 conversion, W tensors only (X conversion fused into proj).
// ---------------------------------------------------------------------------
__global__ __launch_bounds__(256)
void cvt_kernel(const float* __restrict__ wq, const float* __restrict__ wk,
                const float* __restrict__ wv, const float* __restrict__ wo,
                unsigned short* __restrict__ owq, unsigned short* __restrict__ owk,
                unsigned short* __restrict__ owv, unsigned short* __restrict__ owo)
{
  const size_t WN = (size_t)DMODEL * DMODEL;
  const float* s; unsigned short* d;
  switch (blockIdx.y) {
    case 0: s = wq; d = owq; break;
    case 1: s = wk; d = owk; break;
    case 2: s = wv; d = owv; break;
    default: s = wo; d = owo; break;
  }
  for (size_t i = ((size_t)blockIdx.x * 256 + threadIdx.x) * 8; i < WN;
       i += (size_t)gridDim.x * 256 * 8) {
    float4 a = *(const float4*)(s + i);
    float4 b = *(const float4*)(s + i + 4);
    uint4 p = { pack_bf2(a.x, a.y), pack_bf2(a.z, a.w),
                pack_bf2(b.x, b.y), pack_bf2(b.z, b.w) };
    *(uint4*)(d + i) = p;
  }
}

// ---------------------------------------------------------------------------
// Fused-conversion projection GEMM: Out = (Xf32 @ W^T + b) * scale
// A staged fp32->regs->cvt_pk->bf16 LDS (write-side XOR swizzle; rule 21:
// reg-staged writes may scatter, global_load_lds may not).
// W staged bf16 via global_load_lds with global-side pre-swizzle (as before).
// Q/K -> [B,H,S,DK] bf16;  V -> [B,H,DK,SEQ] bf16 (transposed).
// ---------------------------------------------------------------------------
__global__ __launch_bounds__(256, 2)
void proj_bf16_kernel(const float* __restrict__ Xq,
                      const float* __restrict__ Xk,
                      const float* __restrict__ Xv,
                      const unsigned short* __restrict__ Wqc,
                      const unsigned short* __restrict__ Wkc,
                      const unsigned short* __restrict__ Wvc,
                      const float* __restrict__ bq, const float* __restrict__ bk,
                      const float* __restrict__ bv,
                      unsigned short* __restrict__ Qp, unsigned short* __restrict__ Kp,
                      unsigned short* __restrict__ Vp)
{
  const int z = blockIdx.z;
  const float* A = (z == 0) ? Xq : (z == 1) ? Xk : Xv;
  const unsigned short* W = (z == 0) ? Wqc : (z == 1) ? Wkc : Wvc;
  const float* bias = (z == 0) ? bq : (z == 1) ? bk : bv;
  unsigned short* Out = (z == 0) ? Qp : (z == 1) ? Kp : Vp;
  const float scale = (z == 0) ? QSCALE : 1.0f;

  // unpadded [128][64]; LDS[row][u] holds global 16B-unit (u ^ (row&7))
  __shared__ unsigned short As[128 * 64];
  __shared__ unsigned short Bs[128 * 64];

  const int tid  = threadIdx.x;
  const int m0   = blockIdx.x * 128;
  const int n0   = blockIdx.y * 128;
  const int lane = tid & 63;
  const int wave = tid >> 6;
  const int quad = lane >> 4;
  const int l16  = lane & 15;
  const int wm   = (wave >> 1) * 64;
  const int wn   = (wave & 1) * 64;
  const int lrow = lane >> 3;     // 0..7
  const int lcol = lane & 7;      // 16B unit

  const int arow8 = tid >> 3;     // 0..31 (A staging: 8 threads per row)
  const int au    = tid & 7;      // 8-elem (16B bf16) unit within BK=64

  f32x4 acc[4][4];
#pragma unroll
  for (int i = 0; i < 4; ++i)
#pragma unroll
    for (int j = 0; j < 4; ++j) acc[i][j] = (f32x4){0.f, 0.f, 0.f, 0.f};

  for (int k0 = 0; k0 < DMODEL; k0 += 64) {
    // --- A: fp32 global -> regs (issue early) ---
    float4 av[4][2];
#pragma unroll
    for (int g = 0; g < 4; ++g) {
      const float* src = A + (size_t)(m0 + g * 32 + arow8) * DMODEL + k0 + au * 8;
      av[g][0] = *(const float4*)src;
      av[g][1] = *(const float4*)(src + 4);
    }
    // --- W: bf16 via global_load_lds (pre-swizzled source) ---
#pragma unroll
    for (int i = 0; i < 4; ++i) {
      int row = wave * 32 + i * 8 + lrow;
      int gc = (lcol ^ (row & 7)) * 8;
      async_load16(W + (size_t)(n0 + row) * DMODEL + k0 + gc, &Bs[(wave * 32 + i * 8) * 64]);
    }
    // --- A: cvt + swizzled LDS write ---
#pragma unroll
    for (int g = 0; g < 4; ++g) {
      int row = g * 32 + arow8;
      uint4 p = { pack_bf2(av[g][0].x, av[g][0].y), pack_bf2(av[g][0].z, av[g][0].w),
                  pack_bf2(av[g][1].x, av[g][1].y), pack_bf2(av[g][1].z, av[g][1].w) };
      *(uint4*)&As[row * 64 + ((au ^ (row & 7)) * 8)] = p;
    }
    __syncthreads();

#pragma unroll
    for (int ks = 0; ks < 2; ++ks) {
      v8bf af[4], bf[4];
#pragma unroll
      for (int i = 0; i < 4; ++i)
        af[i] = *(const v8bf*)&As[(wm + i * 16 + l16) * 64 + ((ks * 4 + quad) ^ (l16 & 7)) * 8];
#pragma unroll
      for (int j = 0; j < 4; ++j)
        bf[j] = *(const v8bf*)&Bs[(wn + j * 16 + l16) * 64 + ((ks * 4 + quad) ^ (l16 & 7)) * 8];
#pragma unroll
      for (int i = 0; i < 4; ++i)
#pragma unroll
        for (int j = 0; j < 4; ++j)
          acc[i][j] = __builtin_amdgcn_mfma_f32_16x16x32_bf16(af[i], bf[j], acc[i][j], 0, 0, 0);
    }
    __syncthreads();
  }

  if (z < 2) {
    // scatter to [B, H, S, DK] bf16
#pragma unroll
    for (int j = 0; j < 4; ++j) {
      int colg = n0 + wn + j * 16 + l16;
      float bj = bias[colg];
      int h = colg >> 6, d = colg & 63;
#pragma unroll
      for (int i = 0; i < 4; ++i) {
#pragma unroll
        for (int reg = 0; reg < 4; ++reg) {
          int mrow = m0 + wm + i * 16 + quad * 4 + reg;
          int bb = mrow >> 11, ss = mrow & 2047;
          float val = (acc[i][j][reg] + bj) * scale;
          Out[(((size_t)bb * NH + h) * SEQ + ss) * DK + d] = f2bf(val);
        }
      }
    }
  } else {
    // V transposed: [B, H, DK, SEQ]; 4 C-regs = 4 consecutive seq rows
#pragma unroll
    for (int j = 0; j < 4; ++j) {
      int colg = n0 + wn + j * 16 + l16;
      float bj = bias[colg];
      int h = colg >> 6, d = colg & 63;
#pragma unroll
      for (int i = 0; i < 4; ++i) {
        int mrow = m0 + wm + i * 16 + quad * 4;     // 4-aligned
        int bb = mrow >> 11, ss = mrow & 2047;
        uint2 pk = { pack_bf2(acc[i][j][0] + bj, acc[i][j][1] + bj),
                     pack_bf2(acc[i][j][2] + bj, acc[i][j][3] + bj) };
        *(uint2*)(Out + (((size_t)bb * NH + h) * DK + d) * SEQ + ss) = pk;
      }
    }
  }
}

// ---------------------------------------------------------------------------
// Causal flash attention. Block = 128 q-rows x one (b,h). 4 waves; wave w owns
// 32 q-rows. KV chunks of 64, double-buffered LDS via global_load_lds.
// No-max softmax; denominator deferred to epilogue. LDS 40960 B -> 4 blk/CU.
// qt map balances stride-4 residue classes (68 chunks/CU).
// ---------------------------------------------------------------------------
__global__ __launch_bounds__(256, 2)
void attn_kernel(const unsigned short* __restrict__ Qp,
                 const unsigned short* __restrict__ Kp,
                 const unsigned short* __restrict__ VTp,
                 unsigned short* __restrict__ Xout)
{
  const int y  = blockIdx.y;        // 0..15
  const int r  = y & 3, jj = y >> 2;
  const int qt = (jj == 0) ? (15 - r) : (jj == 1) ? (8 + r) : (jj == 2) ? (7 - r) : r;
  const int bh = blockIdx.x;        // 0..63
  const int b  = bh >> 4, h = bh & 15;

  const unsigned short* Qb = Qp  + ((size_t)bh * SEQ + qt * 128) * DK;
  const unsigned short* Kb = Kp  + (size_t)bh * SEQ * DK;
  const unsigned short* Vb = VTp + (size_t)bh * DK * SEQ;   // [DK][SEQ]

  __shared__ unsigned short Ks[2][64 * 64];   // [kv][d], xor-swizzled 16B cols
  __shared__ unsigned short VTs[2][64 * 64];  // [d][kv], xor-swizzled
  __shared__ unsigned short Ps[4][16 * 64];   // per-wave P, group-swizzled

  const int tid  = threadIdx.x;
  const int lane = tid & 63, wave = tid >> 6;
  const int quad = lane >> 4, l16 = lane & 15;
  const int row_lo = qt * 128 + wave * 32;    // this wave's first q row

  // Q fragments straight from global (A-layout: m=l16, k=quad*8+j)
  v8bf qf[2][2];
#pragma unroll
  for (int rf = 0; rf < 2; ++rf)
#pragma unroll
    for (int ks = 0; ks < 2; ++ks)
      qf[rf][ks] = *(const v8bf*)(Qb + (size_t)(wave * 32 + rf * 16 + l16) * DK + ks * 32 + quad * 8);

  float lp[2][4];                   // per-lane partial row sums (denominator)
  f32x4 o[2][4];
#pragma unroll
  for (int rf = 0; rf < 2; ++rf)
#pragma unroll
    for (int reg = 0; reg < 4; ++reg) lp[rf][reg] = 0.f;
#pragma unroll
  for (int rf = 0; rf < 2; ++rf)
#pragma unroll
    for (int df = 0; df < 4; ++df) o[rf][df] = (f32x4){0.f, 0.f, 0.f, 0.f};

  const int nchunk = 2 * (qt + 1);
  const int lrow = lane >> 3;       // 0..7
  const int lcol = lane & 7;        // physical 16B col within row

  // stage chunk 0 into buf 0
#pragma unroll
  for (int is = 0; is < 2; ++is) {
    int row = wave * 16 + is * 8 + lrow;
    int cK = ((lcol ^ (row & 7)) * 8);
    async_load16(Kb + (size_t)row * DK + cK, &Ks[0][(wave * 16 + is * 8) * 64]);
    async_load16(Vb + (size_t)row * SEQ + cK, &VTs[0][(wave * 16 + is * 8) * 64]);
  }
  __syncthreads();

  for (int c = 0; c < nchunk; ++c) {
    const int buf = c & 1;
    const int kb  = c * 64;

    if (c + 1 < nchunk) {
      const int kb2 = kb + 64;
#pragma unroll
      for (int is = 0; is < 2; ++is) {
        int row = wave * 16 + is * 8 + lrow;
        int cc = ((lcol ^ (row & 7)) * 8);
        async_load16(Kb + (size_t)(kb2 + row) * DK + cc, &Ks[buf ^ 1][(wave * 16 + is * 8) * 64]);
        async_load16(Vb + (size_t)row * SEQ + kb2 + cc, &VTs[buf ^ 1][(wave * 16 + is * 8) * 64]);
      }
    }

    if (kb <= row_lo + 31) {    // wave has unmasked work in this chunk
      // ---- S = Q K^T ----
      f32x4 s[2][4];
#pragma unroll
      for (int rf = 0; rf < 2; ++rf)
#pragma unroll
        for (int nf = 0; nf < 4; ++nf) s[rf][nf] = (f32x4){0.f, 0.f, 0.f, 0.f};
#pragma unroll
      for (int ks = 0; ks < 2; ++ks)
#pragma unroll
        for (int nf = 0; nf < 4; ++nf) {
          v8bf kf = *(const v8bf*)&Ks[buf][(nf * 16 + l16) * 64 + ((ks * 4 + quad) ^ (l16 & 7)) * 8];
          s[0][nf] = __builtin_amdgcn_mfma_f32_16x16x32_bf16(qf[0][ks], kf, s[0][nf], 0, 0, 0);
          s[1][nf] = __builtin_amdgcn_mfma_f32_16x16x32_bf16(qf[1][ks], kf, s[1][nf], 0, 0, 0);
        }

      // ---- causal mask (only on diagonal-touching chunks) ----
      if (kb + 63 > row_lo) {
#pragma unroll
        for (int rf = 0; rf < 2; ++rf)
#pragma unroll
          for (int nf = 0; nf < 4; ++nf) {
            int col = kb + nf * 16 + l16;
#pragma unroll
            for (int reg = 0; reg < 4; ++reg)
              if (col > row_lo + rf * 16 + quad * 4 + reg) s[rf][nf][reg] = -1e30f;
          }
      }

      // ---- exp2 (no max subtraction) + deferred denominator + PV ----
#pragma unroll
      for (int rf = 0; rf < 2; ++rf) {
#pragma unroll
        for (int nf = 0; nf < 4; ++nf)
#pragma unroll
          for (int reg = 0; reg < 4; ++reg)
            s[rf][nf][reg] = __builtin_amdgcn_exp2f(s[rf][nf][reg]);
#pragma unroll
        for (int reg = 0; reg < 4; ++reg)
          lp[rf][reg] += (s[rf][0][reg] + s[rf][1][reg]) + (s[rf][2][reg] + s[rf][3][reg]);

        // P: C-layout -> per-wave LDS, swizzled: addr = row*64 + ((g ^ quad*2)*8 + off)
#pragma unroll
        for (int nf = 0; nf < 4; ++nf)
#pragma unroll
          for (int reg = 0; reg < 4; ++reg)
            Ps[wave][(quad * 4 + reg) * 64 +
                     (((nf * 2 + (l16 >> 3)) ^ (quad * 2)) * 8) + (l16 & 7)] =
                f2bf(s[rf][nf][reg]);

        // A-frag read: row=l16, k-group ks*4+quad, unswizzle with key (l16>>2)*2
#pragma unroll
        for (int ks = 0; ks < 2; ++ks) {
          v8bf pf = *(const v8bf*)&Ps[wave][l16 * 64 + (((ks * 4 + quad) ^ ((l16 >> 2) * 2)) * 8)];
#pragma unroll
          for (int df = 0; df < 4; ++df) {
            v8bf vf = *(const v8bf*)&VTs[buf][(df * 16 + l16) * 64 + ((ks * 4 + quad) ^ (l16 & 7)) * 8];
            o[rf][df] = __builtin_amdgcn_mfma_f32_16x16x32_bf16(pf, vf, o[rf][df], 0, 0, 0);
          }
        }
      }
    }
    __syncthreads();   // drains async loads (buf^1) + protects buf for c+2
  }

  // epilogue: one denominator reduction, then [B, S, H*DK] bf16
#pragma unroll
  for (int rf = 0; rf < 2; ++rf) {
#pragma unroll
    for (int off = 1; off < 16; off <<= 1)
#pragma unroll
      for (int reg = 0; reg < 4; ++reg) lp[rf][reg] += __shfl_xor(lp[rf][reg], off);
    float inv[4];
#pragma unroll
    for (int reg = 0; reg < 4; ++reg) inv[reg] = 1.0f / lp[rf][reg];
#pragma unroll
    for (int df = 0; df < 4; ++df)
#pragma unroll
      for (int reg = 0; reg < 4; ++reg) {
        int qrow = row_lo + rf * 16 + quad * 4 + reg;
        Xout[(size_t)(b * SEQ + qrow) * DMODEL + h * DK + df * 16 + l16] =
            f2bf(o[rf][df][reg] * inv[reg]);
      }
  }
}

// ---------------------------------------------------------------------------
// Output projection (bf16 GEMM, fp32 out): d_out = Xa @ Wo^T + bo
// ---------------------------------------------------------------------------
__global__ __launch_bounds__(256, 2)
void oproj_kernel(const unsigned short* __restrict__ Xa,
                  const unsigned short* __restrict__ Woc,
                  const float* __restrict__ bo,
                  float* __restrict__ Out)
{
  __shared__ unsigned short As[128 * 64];
  __shared__ unsigned short Bs[128 * 64];

  const int tid  = threadIdx.x;
  const int m0   = blockIdx.x * 128;
  const int n0   = blockIdx.y * 128;
  const int lane = tid & 63;
  const int wave = tid >> 6;
  const int quad = lane >> 4;
  const int l16  = lane & 15;
  const int wm   = (wave >> 1) * 64;
  const int wn   = (wave & 1) * 64;
  const int lrow = lane >> 3;
  const int lcol = lane & 7;

  f32x4 acc[4][4];
#pragma unroll
  for (int i = 0; i < 4; ++i)
#pragma unroll
    for (int j = 0; j < 4; ++j) acc[i][j] = (f32x4){0.f, 0.f, 0.f, 0.f};

  for (int k0 = 0; k0 < DMODEL; k0 += 64) {
#pragma unroll
    for (int i = 0; i < 4; ++i) {
      int row = wave * 32 + i * 8 + lrow;
      int gc = (lcol ^ (row & 7)) * 8;
      async_load16(Xa  + (size_t)(m0 + row) * DMODEL + k0 + gc, &As[(wave * 32 + i * 8) * 64]);
      async_load16(Woc + (size_t)(n0 + row) * DMODEL + k0 + gc, &Bs[(wave * 32 + i * 8) * 64]);
    }
    __syncthreads();

#pragma unroll
    for (int ks = 0; ks < 2; ++ks) {
      v8bf af[4], bf[4];
#pragma unroll
      for (int i = 0; i < 4; ++i)
        af[i] = *(const v8bf*)&As[(wm + i * 16 + l16) * 64 + ((ks * 4 + quad) ^ (l16 & 7)) * 8];
#pragma unroll
      for (int j = 0; j < 4; ++j)
        bf[j] = *(const v8bf*)&Bs[(wn + j * 16 + l16) * 64 + ((ks * 4 + quad) ^ (l16 & 7)) * 8];
#pragma unroll
      for (int i = 0; i < 4; ++i)
#pragma unroll
        for (int j = 0; j < 4; ++j)
          acc[i][j] = __builtin_amdgcn_mfma_f32_16x16x32_bf16(af[i], bf[j], acc[i][j], 0, 0, 0);
    }
    __syncthreads();
  }

#pragma unroll
  for (int j = 0; j < 4; ++j) {
    int colg = n0 + wn + j * 16 + l16;
    float bj = bo[colg];
#pragma unroll
    for (int i = 0; i < 4; ++i) {
#pragma unroll
      for (int reg = 0; reg < 4; ++reg) {
        int mrow = m0 + wm + i * 16 + quad * 4 + reg;
        Out[(size_t)mrow * DMODEL + colg] = acc[i][j][reg] + bj;
      }
    }
  }
}

extern "C" void kernel_launch(void* const* d_in, const int* in_sizes, int n_in,
                              void* d_out, int out_size, void* d_ws, size_t ws_size,
                              hipStream_t stream)
{
  const float* query = (const float*)d_in[0];
  const float* key   = (const float*)d_in[1];
  const float* value = (const float*)d_in[2];
  const float* Wq = (const float*)d_in[3];
  const float* bq = (const float*)d_in[4];
  const float* Wk = (const float*)d_in[5];
  const float* bk = (const float*)d_in[6];
  const float* Wv = (const float*)d_in[7];
  const float* bv = (const float*)d_in[8];
  const float* Wo = (const float*)d_in[9];
  const float* bo = (const float*)d_in[10];

  const size_t tsz = (size_t)M_TOT * DMODEL;   // elements per bf16 X-tensor
  const size_t wsz = (size_t)DMODEL * DMODEL;  // elements per bf16 W-tensor
  unsigned short* Qp  = (unsigned short*)d_ws;
  unsigned short* Kp  = Qp + tsz;
  unsigned short* Vp  = Kp + tsz;   // transposed per-head: [B,H,DK,SEQ]
  unsigned short* Xa  = Vp + tsz;
  unsigned short* Wqc = Xa + tsz;
  unsigned short* Wkc = Wqc + wsz;
  unsigned short* Wvc = Wkc + wsz;
  unsigned short* Woc = Wvc + wsz;

  cvt_kernel<<<dim3(256, 4), 256, 0, stream>>>(Wq, Wk, Wv, Wo, Wqc, Wkc, Wvc, Woc);
  proj_bf16_kernel<<<dim3(64, 8, 3), 256, 0, stream>>>(query, key, value, Wqc, Wkc, Wvc,
                                                       bq, bk, bv, Qp, Kp, Vp);
  attn_kernel<<<dim3(64, 16), 256, 0, stream>>>(Qp, Kp, Vp, Xa);
  oproj_kernel<<<dim3(64, 8), 256, 0, stream>>>(Xa, Woc, bo, (float*)d_out);
}

// Round 4
// 305.976 us; speedup vs baseline: 1.0368x; 1.0185x over previous
//
#include <hip/hip_runtime.h>
#include <hip/hip_bf16.h>
#include <stdint.h>

#define NH 16
#define SEQ 2048
#define DMODEL 1024
#define DK 64
#define BATCH 4
#define M_TOT 8192  // BATCH * SEQ

#define LOG2E 1.44269504088896f
#define QSCALE (0.125f * LOG2E)   // 1/sqrt(DK) * log2(e), folded into Q

typedef short v8bf __attribute__((ext_vector_type(8)));   // 8 bf16 bit-patterns
typedef float f32x4 __attribute__((ext_vector_type(4)));

// f32->bf16 RNE via compiler intrinsics (compiler-guaranteed pack semantics;
// R1 lesson: raw `v_cvt_pk_bf16_f32` asm had wrong operand order -> O(1) errs).
__device__ __forceinline__ unsigned pack_bf2(float a, float b) {
  union { __hip_bfloat162 h; unsigned u; } v;
  v.h = __float22bfloat162_rn(make_float2(a, b));
  return v.u;
}

__device__ __forceinline__ unsigned short f2bf(float f) {
  union { __hip_bfloat16 h; unsigned short u; } v;
  v.h = __float2bfloat16(f);
  return v.u;
}

// async global->LDS, 16B per lane; LDS dest = wave-uniform base + lane*16
__device__ __forceinline__ void async_load16(const void* g, void* l) {
  __builtin_amdgcn_global_load_lds(
      (const __attribute__((address_space(1))) unsigned int*)(uintptr_t)g,
      (__attribute__((address_space(3))) unsigned int*)(unsigned)(uintptr_t)l,
      16, 0, 0);
}

// ---------------------------------------------------------------------------
// fp32 -> bf16 conversion, W tensors only (X conversion fused into proj).
// ---------------------------------------------------------------------------
__global__ __launch_bounds__(256)
void cvt_kernel(const float* __restrict__ wq, const float* __restrict__ wk,
                const float* __restrict__ wv, const float* __restrict__ wo,
                unsigned short* __restrict__ owq, unsigned short* __restrict__ owk,
                unsigned short* __restrict__ owv, unsigned short* __restrict__ owo)
{
  const size_t WN = (size_t)DMODEL * DMODEL;
  const float* s; unsigned short* d;
  switch (blockIdx.y) {
    case 0: s = wq; d = owq; break;
    case 1: s = wk; d = owk; break;
    case 2: s = wv; d = owv; break;
    default: s = wo; d = owo; break;
  }
  for (size_t i = ((size_t)blockIdx.x * 256 + threadIdx.x) * 8; i < WN;
       i += (size_t)gridDim.x * 256 * 8) {
    float4 a = *(const float4*)(s + i);
    float4 b = *(const float4*)(s + i + 4);
    uint4 p = { pack_bf2(a.x, a.y), pack_bf2(a.z, a.w),
                pack_bf2(b.x, b.y), pack_bf2(b.z, b.w) };
    *(uint4*)(d + i) = p;
  }
}

// ---------------------------------------------------------------------------
// Fused-conversion projection GEMM: Out = (Xf32 @ W^T + b) * scale
// A: fp32 global -> regs, prefetched ONE K-STEP AHEAD (T14 issue-early /
//    write-late; loads-to-VGPR survive barriers), cvt_pk -> swizzled ds_write.
// W: bf16 via global_load_lds with global-side pre-swizzle.
// Q/K -> [B,H,S,DK] bf16;  V -> [B,H,DK,SEQ] bf16 (transposed).
// ---------------------------------------------------------------------------
__global__ __launch_bounds__(256, 2)
void proj_bf16_kernel(const float* __restrict__ Xq,
                      const float* __restrict__ Xk,
                      const float* __restrict__ Xv,
                      const unsigned short* __restrict__ Wqc,
                      const unsigned short* __restrict__ Wkc,
                      const unsigned short* __restrict__ Wvc,
                      const float* __restrict__ bq, const float* __restrict__ bk,
                      const float* __restrict__ bv,
                      unsigned short* __restrict__ Qp, unsigned short* __restrict__ Kp,
                      unsigned short* __restrict__ Vp)
{
  const int z = blockIdx.z;
  const float* A = (z == 0) ? Xq : (z == 1) ? Xk : Xv;
  const unsigned short* W = (z == 0) ? Wqc : (z == 1) ? Wkc : Wvc;
  const float* bias = (z == 0) ? bq : (z == 1) ? bk : bv;
  unsigned short* Out = (z == 0) ? Qp : (z == 1) ? Kp : Vp;
  const float scale = (z == 0) ? QSCALE : 1.0f;

  // unpadded [128][64]; LDS[row][u] holds global 16B-unit (u ^ (row&7))
  __shared__ unsigned short As[128 * 64];
  __shared__ unsigned short Bs[128 * 64];

  const int tid  = threadIdx.x;
  const int m0   = blockIdx.x * 128;
  const int n0   = blockIdx.y * 128;
  const int lane = tid & 63;
  const int wave = tid >> 6;
  const int quad = lane >> 4;
  const int l16  = lane & 15;
  const int wm   = (wave >> 1) * 64;
  const int wn   = (wave & 1) * 64;
  const int lrow = lane >> 3;     // 0..7
  const int lcol = lane & 7;      // 16B unit

  const int arow8 = tid >> 3;     // 0..31 (A staging: 8 threads per row)
  const int au    = tid & 7;      // 8-elem (16B bf16) unit within BK=64

  f32x4 acc[4][4];
#pragma unroll
  for (int i = 0; i < 4; ++i)
#pragma unroll
    for (int j = 0; j < 4; ++j) acc[i][j] = (f32x4){0.f, 0.f, 0.f, 0.f};

  float4 avA[4][2], avB[4][2];

  // K-step sub-ops as macros so every register index stays compile-time.
#define LOAD_X(AV, K0)                                                          \
  {                                                                             \
    _Pragma("unroll")                                                           \
    for (int g = 0; g < 4; ++g) {                                               \
      const float* src = A + (size_t)(m0 + g * 32 + arow8) * DMODEL + (K0) + au * 8; \
      AV[g][0] = *(const float4*)src;                                           \
      AV[g][1] = *(const float4*)(src + 4);                                     \
    }                                                                           \
  }

#define STAGE_W(K0)                                                             \
  {                                                                             \
    _Pragma("unroll")                                                           \
    for (int i = 0; i < 4; ++i) {                                               \
      int row = wave * 32 + i * 8 + lrow;                                       \
      int gc = (lcol ^ (row & 7)) * 8;                                          \
      async_load16(W + (size_t)(n0 + row) * DMODEL + (K0) + gc,                 \
                   &Bs[(wave * 32 + i * 8) * 64]);                              \
    }                                                                           \
  }

#define WRITE_A(AV)                                                             \
  {                                                                             \
    _Pragma("unroll")                                                           \
    for (int g = 0; g < 4; ++g) {                                               \
      int row = g * 32 + arow8;                                                 \
      uint4 p = { pack_bf2(AV[g][0].x, AV[g][0].y), pack_bf2(AV[g][0].z, AV[g][0].w), \
                  pack_bf2(AV[g][1].x, AV[g][1].y), pack_bf2(AV[g][1].z, AV[g][1].w) }; \
      *(uint4*)&As[row * 64 + ((au ^ (row & 7)) * 8)] = p;                      \
    }                                                                           \
  }

#define MFMA_STEP()                                                             \
  {                                                                             \
    _Pragma("unroll")                                                           \
    for (int ks = 0; ks < 2; ++ks) {                                            \
      v8bf af[4], bf[4];                                                        \
      _Pragma("unroll")                                                         \
      for (int i = 0; i < 4; ++i)                                               \
        af[i] = *(const v8bf*)&As[(wm + i * 16 + l16) * 64 + ((ks * 4 + quad) ^ (l16 & 7)) * 8]; \
      _Pragma("unroll")                                                         \
      for (int j = 0; j < 4; ++j)                                               \
        bf[j] = *(const v8bf*)&Bs[(wn + j * 16 + l16) * 64 + ((ks * 4 + quad) ^ (l16 & 7)) * 8]; \
      _Pragma("unroll")                                                         \
      for (int i = 0; i < 4; ++i)                                               \
        _Pragma("unroll")                                                       \
        for (int j = 0; j < 4; ++j)                                             \
          acc[i][j] = __builtin_amdgcn_mfma_f32_16x16x32_bf16(af[i], bf[j], acc[i][j], 0, 0, 0); \
    }                                                                           \
  }

  LOAD_X(avA, 0);
  for (int k0 = 0; k0 < DMODEL; k0 += 128) {
    // ---- step 1: consume avA (k0), prefetch avB (k0+64) ----
    STAGE_W(k0);
    WRITE_A(avA);
    LOAD_X(avB, k0 + 64);          // in flight across the barriers + MFMA
    __syncthreads();
    MFMA_STEP();
    __syncthreads();
    // ---- step 2: consume avB (k0+64), prefetch avA (k0+128) ----
    STAGE_W(k0 + 64);
    WRITE_A(avB);
    if (k0 + 128 < DMODEL) LOAD_X(avA, k0 + 128);
    __syncthreads();
    MFMA_STEP();
    __syncthreads();
  }
#undef LOAD_X
#undef STAGE_W
#undef WRITE_A
#undef MFMA_STEP

  if (z < 2) {
    // scatter to [B, H, S, DK] bf16
#pragma unroll
    for (int j = 0; j < 4; ++j) {
      int colg = n0 + wn + j * 16 + l16;
      float bj = bias[colg];
      int h = colg >> 6, d = colg & 63;
#pragma unroll
      for (int i = 0; i < 4; ++i) {
#pragma unroll
        for (int reg = 0; reg < 4; ++reg) {
          int mrow = m0 + wm + i * 16 + quad * 4 + reg;
          int bb = mrow >> 11, ss = mrow & 2047;
          float val = (acc[i][j][reg] + bj) * scale;
          Out[(((size_t)bb * NH + h) * SEQ + ss) * DK + d] = f2bf(val);
        }
      }
    }
  } else {
    // V transposed: [B, H, DK, SEQ]; 4 C-regs = 4 consecutive seq rows
#pragma unroll
    for (int j = 0; j < 4; ++j) {
      int colg = n0 + wn + j * 16 + l16;
      float bj = bias[colg];
      int h = colg >> 6, d = colg & 63;
#pragma unroll
      for (int i = 0; i < 4; ++i) {
        int mrow = m0 + wm + i * 16 + quad * 4;     // 4-aligned
        int bb = mrow >> 11, ss = mrow & 2047;
        uint2 pk = { pack_bf2(acc[i][j][0] + bj, acc[i][j][1] + bj),
                     pack_bf2(acc[i][j][2] + bj, acc[i][j][3] + bj) };
        *(uint2*)(Out + (((size_t)bb * NH + h) * DK + d) * SEQ + ss) = pk;
      }
    }
  }
}

// ---------------------------------------------------------------------------
// Causal flash attention. Block = 128 q-rows x one (b,h). 4 waves; wave w owns
// 32 q-rows. KV chunks of 64, double-buffered LDS via global_load_lds.
// No-max softmax; denominator deferred to epilogue. LDS 40960 B -> 4 blk/CU.
// qt map balances stride-4 residue classes (68 chunks/CU).
// ---------------------------------------------------------------------------
__global__ __launch_bounds__(256, 2)
void attn_kernel(const unsigned short* __restrict__ Qp,
                 const unsigned short* __restrict__ Kp,
                 const unsigned short* __restrict__ VTp,
                 unsigned short* __restrict__ Xout)
{
  const int y  = blockIdx.y;        // 0..15
  const int r  = y & 3, jj = y >> 2;
  const int qt = (jj == 0) ? (15 - r) : (jj == 1) ? (8 + r) : (jj == 2) ? (7 - r) : r;
  const int bh = blockIdx.x;        // 0..63
  const int b  = bh >> 4, h = bh & 15;

  const unsigned short* Qb = Qp  + ((size_t)bh * SEQ + qt * 128) * DK;
  const unsigned short* Kb = Kp  + (size_t)bh * SEQ * DK;
  const unsigned short* Vb = VTp + (size_t)bh * DK * SEQ;   // [DK][SEQ]

  __shared__ unsigned short Ks[2][64 * 64];   // [kv][d], xor-swizzled 16B cols
  __shared__ unsigned short VTs[2][64 * 64];  // [d][kv], xor-swizzled
  __shared__ unsigned short Ps[4][16 * 64];   // per-wave P, group-swizzled

  const int tid  = threadIdx.x;
  const int lane = tid & 63, wave = tid >> 6;
  const int quad = lane >> 4, l16 = lane & 15;
  const int row_lo = qt * 128 + wave * 32;    // this wave's first q row

  // Q fragments straight from global (A-layout: m=l16, k=quad*8+j)
  v8bf qf[2][2];
#pragma unroll
  for (int rf = 0; rf < 2; ++rf)
#pragma unroll
    for (int ks = 0; ks < 2; ++ks)
      qf[rf][ks] = *(const v8bf*)(Qb + (size_t)(wave * 32 + rf * 16 + l16) * DK + ks * 32 + quad * 8);

  float lp[2][4];                   // per-lane partial row sums (denominator)
  f32x4 o[2][4];
#pragma unroll
  for (int rf = 0; rf < 2; ++rf)
#pragma unroll
    for (int reg = 0; reg < 4; ++reg) lp[rf][reg] = 0.f;
#pragma unroll
  for (int rf = 0; rf < 2; ++rf)
#pragma unroll
    for (int df = 0; df < 4; ++df) o[rf][df] = (f32x4){0.f, 0.f, 0.f, 0.f};

  const int nchunk = 2 * (qt + 1);
  const int lrow = lane >> 3;       // 0..7
  const int lcol = lane & 7;        // physical 16B col within row

  // stage chunk 0 into buf 0
#pragma unroll
  for (int is = 0; is < 2; ++is) {
    int row = wave * 16 + is * 8 + lrow;
    int cK = ((lcol ^ (row & 7)) * 8);
    async_load16(Kb + (size_t)row * DK + cK, &Ks[0][(wave * 16 + is * 8) * 64]);
    async_load16(Vb + (size_t)row * SEQ + cK, &VTs[0][(wave * 16 + is * 8) * 64]);
  }
  __syncthreads();

  for (int c = 0; c < nchunk; ++c) {
    const int buf = c & 1;
    const int kb  = c * 64;

    if (c + 1 < nchunk) {
      const int kb2 = kb + 64;
#pragma unroll
      for (int is = 0; is < 2; ++is) {
        int row = wave * 16 + is * 8 + lrow;
        int cc = ((lcol ^ (row & 7)) * 8);
        async_load16(Kb + (size_t)(kb2 + row) * DK + cc, &Ks[buf ^ 1][(wave * 16 + is * 8) * 64]);
        async_load16(Vb + (size_t)row * SEQ + kb2 + cc, &VTs[buf ^ 1][(wave * 16 + is * 8) * 64]);
      }
    }

    if (kb <= row_lo + 31) {    // wave has unmasked work in this chunk
      // ---- S = Q K^T ----
      f32x4 s[2][4];
#pragma unroll
      for (int rf = 0; rf < 2; ++rf)
#pragma unroll
        for (int nf = 0; nf < 4; ++nf) s[rf][nf] = (f32x4){0.f, 0.f, 0.f, 0.f};
#pragma unroll
      for (int ks = 0; ks < 2; ++ks)
#pragma unroll
        for (int nf = 0; nf < 4; ++nf) {
          v8bf kf = *(const v8bf*)&Ks[buf][(nf * 16 + l16) * 64 + ((ks * 4 + quad) ^ (l16 & 7)) * 8];
          s[0][nf] = __builtin_amdgcn_mfma_f32_16x16x32_bf16(qf[0][ks], kf, s[0][nf], 0, 0, 0);
          s[1][nf] = __builtin_amdgcn_mfma_f32_16x16x32_bf16(qf[1][ks], kf, s[1][nf], 0, 0, 0);
        }

      // ---- causal mask (only on diagonal-touching chunks) ----
      if (kb + 63 > row_lo) {
#pragma unroll
        for (int rf = 0; rf < 2; ++rf)
#pragma unroll
          for (int nf = 0; nf < 4; ++nf) {
            int col = kb + nf * 16 + l16;
#pragma unroll
            for (int reg = 0; reg < 4; ++reg)
              if (col > row_lo + rf * 16 + quad * 4 + reg) s[rf][nf][reg] = -1e30f;
          }
      }

      // ---- exp2 (no max subtraction) + deferred denominator + PV ----
#pragma unroll
      for (int rf = 0; rf < 2; ++rf) {
#pragma unroll
        for (int nf = 0; nf < 4; ++nf)
#pragma unroll
          for (int reg = 0; reg < 4; ++reg)
            s[rf][nf][reg] = __builtin_amdgcn_exp2f(s[rf][nf][reg]);
#pragma unroll
        for (int reg = 0; reg < 4; ++reg)
          lp[rf][reg] += (s[rf][0][reg] + s[rf][1][reg]) + (s[rf][2][reg] + s[rf][3][reg]);

        // P: C-layout -> per-wave LDS, swizzled: addr = row*64 + ((g ^ quad*2)*8 + off)
#pragma unroll
        for (int nf = 0; nf < 4; ++nf)
#pragma unroll
          for (int reg = 0; reg < 4; ++reg)
            Ps[wave][(quad * 4 + reg) * 64 +
                     (((nf * 2 + (l16 >> 3)) ^ (quad * 2)) * 8) + (l16 & 7)] =
                f2bf(s[rf][nf][reg]);

        // A-frag read: row=l16, k-group ks*4+quad, unswizzle with key (l16>>2)*2
#pragma unroll
        for (int ks = 0; ks < 2; ++ks) {
          v8bf pf = *(const v8bf*)&Ps[wave][l16 * 64 + (((ks * 4 + quad) ^ ((l16 >> 2) * 2)) * 8)];
#pragma unroll
          for (int df = 0; df < 4; ++df) {
            v8bf vf = *(const v8bf*)&VTs[buf][(df * 16 + l16) * 64 + ((ks * 4 + quad) ^ (l16 & 7)) * 8];
            o[rf][df] = __builtin_amdgcn_mfma_f32_16x16x32_bf16(pf, vf, o[rf][df], 0, 0, 0);
          }
        }
      }
    }
    __syncthreads();   // drains async loads (buf^1) + protects buf for c+2
  }

  // epilogue: one denominator reduction, then [B, S, H*DK] bf16
#pragma unroll
  for (int rf = 0; rf < 2; ++rf) {
#pragma unroll
    for (int off = 1; off < 16; off <<= 1)
#pragma unroll
      for (int reg = 0; reg < 4; ++reg) lp[rf][reg] += __shfl_xor(lp[rf][reg], off);
    float inv[4];
#pragma unroll
    for (int reg = 0; reg < 4; ++reg) inv[reg] = 1.0f / lp[rf][reg];
#pragma unroll
    for (int df = 0; df < 4; ++df)
#pragma unroll
      for (int reg = 0; reg < 4; ++reg) {
        int qrow = row_lo + rf * 16 + quad * 4 + reg;
        Xout[(size_t)(b * SEQ + qrow) * DMODEL + h * DK + df * 16 + l16] =
            f2bf(o[rf][df][reg] * inv[reg]);
      }
  }
}

// ---------------------------------------------------------------------------
// Output projection (bf16 GEMM, fp32 out): d_out = Xa @ Wo^T + bo
// ---------------------------------------------------------------------------
__global__ __launch_bounds__(256, 2)
void oproj_kernel(const unsigned short* __restrict__ Xa,
                  const unsigned short* __restrict__ Woc,
                  const float* __restrict__ bo,
                  float* __restrict__ Out)
{
  __shared__ unsigned short As[128 * 64];
  __shared__ unsigned short Bs[128 * 64];

  const int tid  = threadIdx.x;
  const int m0   = blockIdx.x * 128;
  const int n0   = blockIdx.y * 128;
  const int lane = tid & 63;
  const int wave = tid >> 6;
  const int quad = lane >> 4;
  const int l16  = lane & 15;
  const int wm   = (wave >> 1) * 64;
  const int wn   = (wave & 1) * 64;
  const int lrow = lane >> 3;
  const int lcol = lane & 7;

  f32x4 acc[4][4];
#pragma unroll
  for (int i = 0; i < 4; ++i)
#pragma unroll
    for (int j = 0; j < 4; ++j) acc[i][j] = (f32x4){0.f, 0.f, 0.f, 0.f};

  for (int k0 = 0; k0 < DMODEL; k0 += 64) {
#pragma unroll
    for (int i = 0; i < 4; ++i) {
      int row = wave * 32 + i * 8 + lrow;
      int gc = (lcol ^ (row & 7)) * 8;
      async_load16(Xa  + (size_t)(m0 + row) * DMODEL + k0 + gc, &As[(wave * 32 + i * 8) * 64]);
      async_load16(Woc + (size_t)(n0 + row) * DMODEL + k0 + gc, &Bs[(wave * 32 + i * 8) * 64]);
    }
    __syncthreads();

#pragma unroll
    for (int ks = 0; ks < 2; ++ks) {
      v8bf af[4], bf[4];
#pragma unroll
      for (int i = 0; i < 4; ++i)
        af[i] = *(const v8bf*)&As[(wm + i * 16 + l16) * 64 + ((ks * 4 + quad) ^ (l16 & 7)) * 8];
#pragma unroll
      for (int j = 0; j < 4; ++j)
        bf[j] = *(const v8bf*)&Bs[(wn + j * 16 + l16) * 64 + ((ks * 4 + quad) ^ (l16 & 7)) * 8];
#pragma unroll
      for (int i = 0; i < 4; ++i)
#pragma unroll
        for (int j = 0; j < 4; ++j)
          acc[i][j] = __builtin_amdgcn_mfma_f32_16x16x32_bf16(af[i], bf[j], acc[i][j], 0, 0, 0);
    }
    __syncthreads();
  }

#pragma unroll
  for (int j = 0; j < 4; ++j) {
    int colg = n0 + wn + j * 16 + l16;
    float bj = bo[colg];
#pragma unroll
    for (int i = 0; i < 4; ++i) {
#pragma unroll
      for (int reg = 0; reg < 4; ++reg) {
        int mrow = m0 + wm + i * 16 + quad * 4 + reg;
        Out[(size_t)mrow * DMODEL + colg] = acc[i][j][reg] + bj;
      }
    }
  }
}

extern "C" void kernel_launch(void* const* d_in, const int* in_sizes, int n_in,
                              void* d_out, int out_size, void* d_ws, size_t ws_size,
                              hipStream_t stream)
{
  const float* query = (const float*)d_in[0];
  const float* key   = (const float*)d_in[1];
  const float* value = (const float*)d_in[2];
  const float* Wq = (const float*)d_in[3];
  const float* bq = (const float*)d_in[4];
  const float* Wk = (const float*)d_in[5];
  const float* bk = (const float*)d_in[6];
  const float* Wv = (const float*)d_in[7];
  const float* bv = (const float*)d_in[8];
  const float* Wo = (const float*)d_in[9];
  const float* bo = (const float*)d_in[10];

  const size_t tsz = (size_t)M_TOT * DMODEL;   // elements per bf16 X-tensor
  const size_t wsz = (size_t)DMODEL * DMODEL;  // elements per bf16 W-tensor
  unsigned short* Qp  = (unsigned short*)d_ws;
  unsigned short* Kp  = Qp + tsz;
  unsigned short* Vp  = Kp + tsz;   // transposed per-head: [B,H,DK,SEQ]
  unsigned short* Xa  = Vp + tsz;
  unsigned short* Wqc = Xa + tsz;
  unsigned short* Wkc = Wqc + wsz;
  unsigned short* Wvc = Wkc + wsz;
  unsigned short* Woc = Wvc + wsz;

  cvt_kernel<<<dim3(256, 4), 256, 0, stream>>>(Wq, Wk, Wv, Wo, Wqc, Wkc, Wvc, Woc);
  proj_bf16_kernel<<<dim3(64, 8, 3), 256, 0, stream>>>(query, key, value, Wqc, Wkc, Wvc,
                                                       bq, bk, bv, Qp, Kp, Vp);
  attn_kernel<<<dim3(64, 16), 256, 0, stream>>>(Qp, Kp, Vp, Xa);
  oproj_kernel<<<dim3(64, 8), 256, 0, stream>>>(Xa, Woc, bo, (float*)d_out);
}

// Round 5
// 298.754 us; speedup vs baseline: 1.0619x; 1.0242x over previous
//
#include <hip/hip_runtime.h>
#include <hip/hip_bf16.h>
#include <stdint.h>

#define NH 16
#define SEQ 2048
#define DMODEL 1024
#define DK 64
#define BATCH 4
#define M_TOT 8192  // BATCH * SEQ

#define LOG2E 1.44269504088896f
#define QSCALE (0.125f * LOG2E)   // 1/sqrt(DK) * log2(e), folded into Q

typedef short v8bf __attribute__((ext_vector_type(8)));   // 8 bf16 bit-patterns
typedef float f32x4 __attribute__((ext_vector_type(4)));

// f32->bf16 RNE via compiler intrinsics (compiler-guaranteed pack semantics;
// R1 lesson: raw `v_cvt_pk_bf16_f32` asm graft had wrong operand semantics).
__device__ __forceinline__ unsigned pack_bf2(float a, float b) {
  union { __hip_bfloat162 h; unsigned u; } v;
  v.h = __float22bfloat162_rn(make_float2(a, b));
  return v.u;
}

__device__ __forceinline__ unsigned short f2bf(float f) {
  union { __hip_bfloat16 h; unsigned short u; } v;
  v.h = __float2bfloat16(f);
  return v.u;
}

// async global->LDS, 16B per lane; LDS dest = wave-uniform base + lane*16
__device__ __forceinline__ void async_load16(const void* g, void* l) {
  __builtin_amdgcn_global_load_lds(
      (const __attribute__((address_space(1))) unsigned int*)(uintptr_t)g,
      (__attribute__((address_space(3))) unsigned int*)(unsigned)(uintptr_t)l,
      16, 0, 0);
}

// ---------------------------------------------------------------------------
// fp32 -> bf16 bulk conversion: query/key/value + Wq/Wk/Wv/Wo.
// (R3/R4 fused the X conversion into proj: measured NET LOSS — conversion
//  re-done per N-tile and A-path lost global_load_lds. Keep the split.)
// ---------------------------------------------------------------------------
__global__ __launch_bounds__(256)
void cvt_kernel(const float* __restrict__ q, const float* __restrict__ k,
                const float* __restrict__ v,
                const float* __restrict__ wq, const float* __restrict__ wk,
                const float* __restrict__ wv, const float* __restrict__ wo,
                unsigned short* __restrict__ oq, unsigned short* __restrict__ ok,
                unsigned short* __restrict__ ov,
                unsigned short* __restrict__ owq, unsigned short* __restrict__ owk,
                unsigned short* __restrict__ owv, unsigned short* __restrict__ owo)
{
  const size_t XN = (size_t)M_TOT * DMODEL;
  const size_t WN = (size_t)DMODEL * DMODEL;
  const float* s; unsigned short* d; size_t n;
  switch (blockIdx.y) {
    case 0: s = q;  d = oq;  n = XN; break;
    case 1: s = k;  d = ok;  n = XN; break;
    case 2: s = v;  d = ov;  n = XN; break;
    case 3: s = wq; d = owq; n = WN; break;
    case 4: s = wk; d = owk; n = WN; break;
    case 5: s = wv; d = owv; n = WN; break;
    default: s = wo; d = owo; n = WN; break;
  }
  for (size_t i = ((size_t)blockIdx.x * 256 + threadIdx.x) * 8; i < n;
       i += (size_t)gridDim.x * 256 * 8) {
    float4 a = *(const float4*)(s + i);
    float4 b = *(const float4*)(s + i + 4);
    uint4 p = { pack_bf2(a.x, a.y), pack_bf2(a.z, a.w),
                pack_bf2(b.x, b.y), pack_bf2(b.z, b.w) };
    *(uint4*)(d + i) = p;
  }
}

// ---------------------------------------------------------------------------
// bf16 projection GEMM (m97-style): Out = (X @ W^T + b) * scale
// 128x128 tile, BK=64, global_load_lds staging, XOR-swizzled LDS cols.
// Q/K -> [B,H,S,DK] bf16;  V -> [B,H,DK,SEQ] bf16 (transposed).
// ---------------------------------------------------------------------------
__global__ __launch_bounds__(256, 2)
void proj_bf16_kernel(const unsigned short* __restrict__ Xq,
                      const unsigned short* __restrict__ Xk,
                      const unsigned short* __restrict__ Xv,
                      const unsigned short* __restrict__ Wqc,
                      const unsigned short* __restrict__ Wkc,
                      const unsigned short* __restrict__ Wvc,
                      const float* __restrict__ bq, const float* __restrict__ bk,
                      const float* __restrict__ bv,
                      unsigned short* __restrict__ Qp, unsigned short* __restrict__ Kp,
                      unsigned short* __restrict__ Vp)
{
  const int z = blockIdx.z;
  const unsigned short* A = (z == 0) ? Xq : (z == 1) ? Xk : Xv;
  const unsigned short* W = (z == 0) ? Wqc : (z == 1) ? Wkc : Wvc;
  const float* bias = (z == 0) ? bq : (z == 1) ? bk : bv;
  unsigned short* Out = (z == 0) ? Qp : (z == 1) ? Kp : Vp;
  const float scale = (z == 0) ? QSCALE : 1.0f;

  // unpadded [128][64]; LDS[row][u] = global[row][u ^ (row&7)] (16B units)
  __shared__ unsigned short As[128 * 64];
  __shared__ unsigned short Bs[128 * 64];

  const int tid  = threadIdx.x;
  const int m0   = blockIdx.x * 128;
  const int n0   = blockIdx.y * 128;
  const int lane = tid & 63;
  const int wave = tid >> 6;
  const int quad = lane >> 4;
  const int l16  = lane & 15;
  const int wm   = (wave >> 1) * 64;
  const int wn   = (wave & 1) * 64;
  const int lrow = lane >> 3;     // 0..7
  const int lcol = lane & 7;      // 16B unit

  f32x4 acc[4][4];
#pragma unroll
  for (int i = 0; i < 4; ++i)
#pragma unroll
    for (int j = 0; j < 4; ++j) acc[i][j] = (f32x4){0.f, 0.f, 0.f, 0.f};

  for (int k0 = 0; k0 < DMODEL; k0 += 64) {
#pragma unroll
    for (int i = 0; i < 4; ++i) {
      int row = wave * 32 + i * 8 + lrow;
      int gc = (lcol ^ (row & 7)) * 8;    // element offset within BK
      async_load16(A + (size_t)(m0 + row) * DMODEL + k0 + gc, &As[(wave * 32 + i * 8) * 64]);
      async_load16(W + (size_t)(n0 + row) * DMODEL + k0 + gc, &Bs[(wave * 32 + i * 8) * 64]);
    }
    __syncthreads();

#pragma unroll
    for (int ks = 0; ks < 2; ++ks) {
      v8bf af[4], bf[4];
#pragma unroll
      for (int i = 0; i < 4; ++i)
        af[i] = *(const v8bf*)&As[(wm + i * 16 + l16) * 64 + ((ks * 4 + quad) ^ (l16 & 7)) * 8];
#pragma unroll
      for (int j = 0; j < 4; ++j)
        bf[j] = *(const v8bf*)&Bs[(wn + j * 16 + l16) * 64 + ((ks * 4 + quad) ^ (l16 & 7)) * 8];
#pragma unroll
      for (int i = 0; i < 4; ++i)
#pragma unroll
        for (int j = 0; j < 4; ++j)
          acc[i][j] = __builtin_amdgcn_mfma_f32_16x16x32_bf16(af[i], bf[j], acc[i][j], 0, 0, 0);
    }
    __syncthreads();
  }

  if (z < 2) {
    // scatter to [B, H, S, DK] bf16
#pragma unroll
    for (int j = 0; j < 4; ++j) {
      int colg = n0 + wn + j * 16 + l16;
      float bj = bias[colg];
      int h = colg >> 6, d = colg & 63;
#pragma unroll
      for (int i = 0; i < 4; ++i) {
#pragma unroll
        for (int reg = 0; reg < 4; ++reg) {
          int mrow = m0 + wm + i * 16 + quad * 4 + reg;
          int bb = mrow >> 11, ss = mrow & 2047;
          float val = (acc[i][j][reg] + bj) * scale;
          Out[(((size_t)bb * NH + h) * SEQ + ss) * DK + d] = f2bf(val);
        }
      }
    }
  } else {
    // V transposed: [B, H, DK, SEQ]; 4 C-regs = 4 consecutive seq rows
#pragma unroll
    for (int j = 0; j < 4; ++j) {
      int colg = n0 + wn + j * 16 + l16;
      float bj = bias[colg];
      int h = colg >> 6, d = colg & 63;
#pragma unroll
      for (int i = 0; i < 4; ++i) {
        int mrow = m0 + wm + i * 16 + quad * 4;     // 4-aligned
        int bb = mrow >> 11, ss = mrow & 2047;
        uint2 pk = { pack_bf2(acc[i][j][0] + bj, acc[i][j][1] + bj),
                     pack_bf2(acc[i][j][2] + bj, acc[i][j][3] + bj) };
        *(uint2*)(Out + (((size_t)bb * NH + h) * DK + d) * SEQ + ss) = pk;
      }
    }
  }
}

// ---------------------------------------------------------------------------
// Causal flash attention. Block = 128 q-rows x one (b,h). 4 waves; wave w owns
// 32 q-rows. KV chunks of 64, double-buffered LDS via global_load_lds.
// No-max softmax; denominator deferred to epilogue. LDS 40960 B -> 4 blk/CU.
// qt map balances stride-4 residue classes (68 chunks/CU).
// T5: s_setprio(1) around MFMA clusters (m191: +4-7% on attn-regime kernels
// with independent per-CU blocks at different phases; correctness-neutral).
// ---------------------------------------------------------------------------
__global__ __launch_bounds__(256, 2)
void attn_kernel(const unsigned short* __restrict__ Qp,
                 const unsigned short* __restrict__ Kp,
                 const unsigned short* __restrict__ VTp,
                 unsigned short* __restrict__ Xout)
{
  const int y  = blockIdx.y;        // 0..15
  const int r  = y & 3, jj = y >> 2;
  const int qt = (jj == 0) ? (15 - r) : (jj == 1) ? (8 + r) : (jj == 2) ? (7 - r) : r;
  const int bh = blockIdx.x;        // 0..63
  const int b  = bh >> 4, h = bh & 15;

  const unsigned short* Qb = Qp  + ((size_t)bh * SEQ + qt * 128) * DK;
  const unsigned short* Kb = Kp  + (size_t)bh * SEQ * DK;
  const unsigned short* Vb = VTp + (size_t)bh * DK * SEQ;   // [DK][SEQ]

  __shared__ unsigned short Ks[2][64 * 64];   // [kv][d], xor-swizzled 16B cols
  __shared__ unsigned short VTs[2][64 * 64];  // [d][kv], xor-swizzled
  __shared__ unsigned short Ps[4][16 * 64];   // per-wave P, group-swizzled

  const int tid  = threadIdx.x;
  const int lane = tid & 63, wave = tid >> 6;
  const int quad = lane >> 4, l16 = lane & 15;
  const int row_lo = qt * 128 + wave * 32;    // this wave's first q row

  // Q fragments straight from global (A-layout: m=l16, k=quad*8+j)
  v8bf qf[2][2];
#pragma unroll
  for (int rf = 0; rf < 2; ++rf)
#pragma unroll
    for (int ks = 0; ks < 2; ++ks)
      qf[rf][ks] = *(const v8bf*)(Qb + (size_t)(wave * 32 + rf * 16 + l16) * DK + ks * 32 + quad * 8);

  float lp[2][4];                   // per-lane partial row sums (denominator)
  f32x4 o[2][4];
#pragma unroll
  for (int rf = 0; rf < 2; ++rf)
#pragma unroll
    for (int reg = 0; reg < 4; ++reg) lp[rf][reg] = 0.f;
#pragma unroll
  for (int rf = 0; rf < 2; ++rf)
#pragma unroll
    for (int df = 0; df < 4; ++df) o[rf][df] = (f32x4){0.f, 0.f, 0.f, 0.f};

  const int nchunk = 2 * (qt + 1);
  const int lrow = lane >> 3;       // 0..7
  const int lcol = lane & 7;        // physical 16B col within row

  // stage chunk 0 into buf 0
#pragma unroll
  for (int is = 0; is < 2; ++is) {
    int row = wave * 16 + is * 8 + lrow;
    int cK = ((lcol ^ (row & 7)) * 8);
    async_load16(Kb + (size_t)row * DK + cK, &Ks[0][(wave * 16 + is * 8) * 64]);
    async_load16(Vb + (size_t)row * SEQ + cK, &VTs[0][(wave * 16 + is * 8) * 64]);
  }
  __syncthreads();

  for (int c = 0; c < nchunk; ++c) {
    const int buf = c & 1;
    const int kb  = c * 64;

    if (c + 1 < nchunk) {
      const int kb2 = kb + 64;
#pragma unroll
      for (int is = 0; is < 2; ++is) {
        int row = wave * 16 + is * 8 + lrow;
        int cc = ((lcol ^ (row & 7)) * 8);
        async_load16(Kb + (size_t)(kb2 + row) * DK + cc, &Ks[buf ^ 1][(wave * 16 + is * 8) * 64]);
        async_load16(Vb + (size_t)row * SEQ + kb2 + cc, &VTs[buf ^ 1][(wave * 16 + is * 8) * 64]);
      }
    }

    if (kb <= row_lo + 31) {    // wave has unmasked work in this chunk
      // ---- S = Q K^T ----
      f32x4 s[2][4];
#pragma unroll
      for (int rf = 0; rf < 2; ++rf)
#pragma unroll
        for (int nf = 0; nf < 4; ++nf) s[rf][nf] = (f32x4){0.f, 0.f, 0.f, 0.f};
      __builtin_amdgcn_s_setprio(1);
#pragma unroll
      for (int ks = 0; ks < 2; ++ks)
#pragma unroll
        for (int nf = 0; nf < 4; ++nf) {
          v8bf kf = *(const v8bf*)&Ks[buf][(nf * 16 + l16) * 64 + ((ks * 4 + quad) ^ (l16 & 7)) * 8];
          s[0][nf] = __builtin_amdgcn_mfma_f32_16x16x32_bf16(qf[0][ks], kf, s[0][nf], 0, 0, 0);
          s[1][nf] = __builtin_amdgcn_mfma_f32_16x16x32_bf16(qf[1][ks], kf, s[1][nf], 0, 0, 0);
        }
      __builtin_amdgcn_s_setprio(0);

      // ---- causal mask (only on diagonal-touching chunks) ----
      if (kb + 63 > row_lo) {
#pragma unroll
        for (int rf = 0; rf < 2; ++rf)
#pragma unroll
          for (int nf = 0; nf < 4; ++nf) {
            int col = kb + nf * 16 + l16;
#pragma unroll
            for (int reg = 0; reg < 4; ++reg)
              if (col > row_lo + rf * 16 + quad * 4 + reg) s[rf][nf][reg] = -1e30f;
          }
      }

      // ---- exp2 (no max subtraction) + deferred denominator + PV ----
#pragma unroll
      for (int rf = 0; rf < 2; ++rf) {
#pragma unroll
        for (int nf = 0; nf < 4; ++nf)
#pragma unroll
          for (int reg = 0; reg < 4; ++reg)
            s[rf][nf][reg] = __builtin_amdgcn_exp2f(s[rf][nf][reg]);
#pragma unroll
        for (int reg = 0; reg < 4; ++reg)
          lp[rf][reg] += (s[rf][0][reg] + s[rf][1][reg]) + (s[rf][2][reg] + s[rf][3][reg]);

        // P: C-layout -> per-wave LDS, swizzled: addr = row*64 + ((g ^ quad*2)*8 + off)
#pragma unroll
        for (int nf = 0; nf < 4; ++nf)
#pragma unroll
          for (int reg = 0; reg < 4; ++reg)
            Ps[wave][(quad * 4 + reg) * 64 +
                     (((nf * 2 + (l16 >> 3)) ^ (quad * 2)) * 8) + (l16 & 7)] =
                f2bf(s[rf][nf][reg]);

        // A-frag read: row=l16, k-group ks*4+quad, unswizzle with key (l16>>2)*2
        __builtin_amdgcn_s_setprio(1);
#pragma unroll
        for (int ks = 0; ks < 2; ++ks) {
          v8bf pf = *(const v8bf*)&Ps[wave][l16 * 64 + (((ks * 4 + quad) ^ ((l16 >> 2) * 2)) * 8)];
#pragma unroll
          for (int df = 0; df < 4; ++df) {
            v8bf vf = *(const v8bf*)&VTs[buf][(df * 16 + l16) * 64 + ((ks * 4 + quad) ^ (l16 & 7)) * 8];
            o[rf][df] = __builtin_amdgcn_mfma_f32_16x16x32_bf16(pf, vf, o[rf][df], 0, 0, 0);
          }
        }
        __builtin_amdgcn_s_setprio(0);
      }
    }
    __syncthreads();   // drains async loads (buf^1) + protects buf for c+2
  }

  // epilogue: one denominator reduction, then [B, S, H*DK] bf16
#pragma unroll
  for (int rf = 0; rf < 2; ++rf) {
#pragma unroll
    for (int off = 1; off < 16; off <<= 1)
#pragma unroll
      for (int reg = 0; reg < 4; ++reg) lp[rf][reg] += __shfl_xor(lp[rf][reg], off);
    float inv[4];
#pragma unroll
    for (int reg = 0; reg < 4; ++reg) inv[reg] = 1.0f / lp[rf][reg];
#pragma unroll
    for (int df = 0; df < 4; ++df)
#pragma unroll
      for (int reg = 0; reg < 4; ++reg) {
        int qrow = row_lo + rf * 16 + quad * 4 + reg;
        Xout[(size_t)(b * SEQ + qrow) * DMODEL + h * DK + df * 16 + l16] =
            f2bf(o[rf][df][reg] * inv[reg]);
      }
  }
}

// ---------------------------------------------------------------------------
// Output projection (bf16 GEMM, fp32 out): d_out = Xa @ Wo^T + bo
// ---------------------------------------------------------------------------
__global__ __launch_bounds__(256, 2)
void oproj_kernel(const unsigned short* __restrict__ Xa,
                  const unsigned short* __restrict__ Woc,
                  const float* __restrict__ bo,
                  float* __restrict__ Out)
{
  __shared__ unsigned short As[128 * 64];
  __shared__ unsigned short Bs[128 * 64];

  const int tid  = threadIdx.x;
  const int m0   = blockIdx.x * 128;
  const int n0   = blockIdx.y * 128;
  const int lane = tid & 63;
  const int wave = tid >> 6;
  const int quad = lane >> 4;
  const int l16  = lane & 15;
  const int wm   = (wave >> 1) * 64;
  const int wn   = (wave & 1) * 64;
  const int lrow = lane >> 3;
  const int lcol = lane & 7;

  f32x4 acc[4][4];
#pragma unroll
  for (int i = 0; i < 4; ++i)
#pragma unroll
    for (int j = 0; j < 4; ++j) acc[i][j] = (f32x4){0.f, 0.f, 0.f, 0.f};

  for (int k0 = 0; k0 < DMODEL; k0 += 64) {
#pragma unroll
    for (int i = 0; i < 4; ++i) {
      int row = wave * 32 + i * 8 + lrow;
      int gc = (lcol ^ (row & 7)) * 8;
      async_load16(Xa  + (size_t)(m0 + row) * DMODEL + k0 + gc, &As[(wave * 32 + i * 8) * 64]);
      async_load16(Woc + (size_t)(n0 + row) * DMODEL + k0 + gc, &Bs[(wave * 32 + i * 8) * 64]);
    }
    __syncthreads();

#pragma unroll
    for (int ks = 0; ks < 2; ++ks) {
      v8bf af[4], bf[4];
#pragma unroll
      for (int i = 0; i < 4; ++i)
        af[i] = *(const v8bf*)&As[(wm + i * 16 + l16) * 64 + ((ks * 4 + quad) ^ (l16 & 7)) * 8];
#pragma unroll
      for (int j = 0; j < 4; ++j)
        bf[j] = *(const v8bf*)&Bs[(wn + j * 16 + l16) * 64 + ((ks * 4 + quad) ^ (l16 & 7)) * 8];
#pragma unroll
      for (int i = 0; i < 4; ++i)
#pragma unroll
        for (int j = 0; j < 4; ++j)
          acc[i][j] = __builtin_amdgcn_mfma_f32_16x16x32_bf16(af[i], bf[j], acc[i][j], 0, 0, 0);
    }
    __syncthreads();
  }

#pragma unroll
  for (int j = 0; j < 4; ++j) {
    int colg = n0 + wn + j * 16 + l16;
    float bj = bo[colg];
#pragma unroll
    for (int i = 0; i < 4; ++i) {
#pragma unroll
      for (int reg = 0; reg < 4; ++reg) {
        int mrow = m0 + wm + i * 16 + quad * 4 + reg;
        Out[(size_t)mrow * DMODEL + colg] = acc[i][j][reg] + bj;
      }
    }
  }
}

extern "C" void kernel_launch(void* const* d_in, const int* in_sizes, int n_in,
                              void* d_out, int out_size, void* d_ws, size_t ws_size,
                              hipStream_t stream)
{
  const float* query = (const float*)d_in[0];
  const float* key   = (const float*)d_in[1];
  const float* value = (const float*)d_in[2];
  const float* Wq = (const float*)d_in[3];
  const float* bq = (const float*)d_in[4];
  const float* Wk = (const float*)d_in[5];
  const float* bk = (const float*)d_in[6];
  const float* Wv = (const float*)d_in[7];
  const float* bv = (const float*)d_in[8];
  const float* Wo = (const float*)d_in[9];
  const float* bo = (const float*)d_in[10];

  const size_t tsz = (size_t)M_TOT * DMODEL;   // elements per bf16 X-tensor
  const size_t wsz = (size_t)DMODEL * DMODEL;  // elements per bf16 W-tensor
  unsigned short* Qp  = (unsigned short*)d_ws;
  unsigned short* Kp  = Qp + tsz;
  unsigned short* Vp  = Kp + tsz;   // transposed per-head: [B,H,DK,SEQ]
  unsigned short* Xa  = Vp + tsz;
  unsigned short* Xqc = Xa + tsz;
  unsigned short* Xkc = Xqc + tsz;
  unsigned short* Xvc = Xkc + tsz;
  unsigned short* Wqc = Xvc + tsz;
  unsigned short* Wkc = Wqc + wsz;
  unsigned short* Wvc = Wkc + wsz;
  unsigned short* Woc = Wvc + wsz;

  cvt_kernel<<<dim3(1024, 7), 256, 0, stream>>>(query, key, value, Wq, Wk, Wv, Wo,
                                                Xqc, Xkc, Xvc, Wqc, Wkc, Wvc, Woc);
  proj_bf16_kernel<<<dim3(64, 8, 3), 256, 0, stream>>>(Xqc, Xkc, Xvc, Wqc, Wkc, Wvc,
                                                       bq, bk, bv, Qp, Kp, Vp);
  attn_kernel<<<dim3(64, 16), 256, 0, stream>>>(Qp, Kp, Vp, Xa);
  oproj_kernel<<<dim3(64, 8), 256, 0, stream>>>(Xa, Woc, bo, (float*)d_out);
}

// Round 6
// 298.642 us; speedup vs baseline: 1.0623x; 1.0004x over previous
//
#include <hip/hip_runtime.h>
#include <hip/hip_bf16.h>
#include <stdint.h>

#define NH 16
#define SEQ 2048
#define DMODEL 1024
#define DK 64
#define BATCH 4
#define M_TOT 8192  // BATCH * SEQ

#define LOG2E 1.44269504088896f
#define QSCALE (0.125f * LOG2E)   // 1/sqrt(DK) * log2(e), folded into Q

typedef short v8bf __attribute__((ext_vector_type(8)));   // 8 bf16 bit-patterns
typedef float f32x4 __attribute__((ext_vector_type(4)));

// f32->bf16 RNE via compiler intrinsics (compiler-guaranteed pack semantics;
// R1 lesson: raw `v_cvt_pk_bf16_f32` asm graft had wrong operand semantics).
__device__ __forceinline__ unsigned pack_bf2(float a, float b) {
  union { __hip_bfloat162 h; unsigned u; } v;
  v.h = __float22bfloat162_rn(make_float2(a, b));
  return v.u;
}

__device__ __forceinline__ unsigned short f2bf(float f) {
  union { __hip_bfloat16 h; unsigned short u; } v;
  v.h = __float2bfloat16(f);
  return v.u;
}

// async global->LDS, 16B per lane; LDS dest = wave-uniform base + lane*16
__device__ __forceinline__ void async_load16(const void* g, void* l) {
  __builtin_amdgcn_global_load_lds(
      (const __attribute__((address_space(1))) unsigned int*)(uintptr_t)g,
      (__attribute__((address_space(3))) unsigned int*)(unsigned)(uintptr_t)l,
      16, 0, 0);
}

// ---------------------------------------------------------------------------
// fp32 -> bf16 bulk conversion: query/key/value + Wq/Wk/Wv/Wo.
// (R3/R4 fused the X conversion into proj: measured NET LOSS — conversion
//  re-done per N-tile and A-path lost global_load_lds. Keep the split.)
// ---------------------------------------------------------------------------
__global__ __launch_bounds__(256)
void cvt_kernel(const float* __restrict__ q, const float* __restrict__ k,
                const float* __restrict__ v,
                const float* __restrict__ wq, const float* __restrict__ wk,
                const float* __restrict__ wv, const float* __restrict__ wo,
                unsigned short* __restrict__ oq, unsigned short* __restrict__ ok,
                unsigned short* __restrict__ ov,
                unsigned short* __restrict__ owq, unsigned short* __restrict__ owk,
                unsigned short* __restrict__ owv, unsigned short* __restrict__ owo)
{
  const size_t XN = (size_t)M_TOT * DMODEL;
  const size_t WN = (size_t)DMODEL * DMODEL;
  const float* s; unsigned short* d; size_t n;
  switch (blockIdx.y) {
    case 0: s = q;  d = oq;  n = XN; break;
    case 1: s = k;  d = ok;  n = XN; break;
    case 2: s = v;  d = ov;  n = XN; break;
    case 3: s = wq; d = owq; n = WN; break;
    case 4: s = wk; d = owk; n = WN; break;
    case 5: s = wv; d = owv; n = WN; break;
    default: s = wo; d = owo; n = WN; break;
  }
  for (size_t i = ((size_t)blockIdx.x * 256 + threadIdx.x) * 8; i < n;
       i += (size_t)gridDim.x * 256 * 8) {
    float4 a = *(const float4*)(s + i);
    float4 b = *(const float4*)(s + i + 4);
    uint4 p = { pack_bf2(a.x, a.y), pack_bf2(a.z, a.w),
                pack_bf2(b.x, b.y), pack_bf2(b.z, b.w) };
    *(uint4*)(d + i) = p;
  }
}

// ---------------------------------------------------------------------------
// bf16 projection GEMM (m97-style): Out = (X @ W^T + b) * scale
// 128x128 tile, BK=64, global_load_lds staging, XOR-swizzled LDS cols.
// Q/K -> [B,H,S,DK] bf16;  V -> [B,H,DK,SEQ] bf16 (transposed).
// ---------------------------------------------------------------------------
__global__ __launch_bounds__(256, 2)
void proj_bf16_kernel(const unsigned short* __restrict__ Xq,
                      const unsigned short* __restrict__ Xk,
                      const unsigned short* __restrict__ Xv,
                      const unsigned short* __restrict__ Wqc,
                      const unsigned short* __restrict__ Wkc,
                      const unsigned short* __restrict__ Wvc,
                      const float* __restrict__ bq, const float* __restrict__ bk,
                      const float* __restrict__ bv,
                      unsigned short* __restrict__ Qp, unsigned short* __restrict__ Kp,
                      unsigned short* __restrict__ Vp)
{
  const int z = blockIdx.z;
  const unsigned short* A = (z == 0) ? Xq : (z == 1) ? Xk : Xv;
  const unsigned short* W = (z == 0) ? Wqc : (z == 1) ? Wkc : Wvc;
  const float* bias = (z == 0) ? bq : (z == 1) ? bk : bv;
  unsigned short* Out = (z == 0) ? Qp : (z == 1) ? Kp : Vp;
  const float scale = (z == 0) ? QSCALE : 1.0f;

  // unpadded [128][64]; LDS[row][u] = global[row][u ^ (row&7)] (16B units)
  __shared__ unsigned short As[128 * 64];
  __shared__ unsigned short Bs[128 * 64];

  const int tid  = threadIdx.x;
  const int m0   = blockIdx.x * 128;
  const int n0   = blockIdx.y * 128;
  const int lane = tid & 63;
  const int wave = tid >> 6;
  const int quad = lane >> 4;
  const int l16  = lane & 15;
  const int wm   = (wave >> 1) * 64;
  const int wn   = (wave & 1) * 64;
  const int lrow = lane >> 3;     // 0..7
  const int lcol = lane & 7;      // 16B unit

  f32x4 acc[4][4];
#pragma unroll
  for (int i = 0; i < 4; ++i)
#pragma unroll
    for (int j = 0; j < 4; ++j) acc[i][j] = (f32x4){0.f, 0.f, 0.f, 0.f};

  for (int k0 = 0; k0 < DMODEL; k0 += 64) {
#pragma unroll
    for (int i = 0; i < 4; ++i) {
      int row = wave * 32 + i * 8 + lrow;
      int gc = (lcol ^ (row & 7)) * 8;    // element offset within BK
      async_load16(A + (size_t)(m0 + row) * DMODEL + k0 + gc, &As[(wave * 32 + i * 8) * 64]);
      async_load16(W + (size_t)(n0 + row) * DMODEL + k0 + gc, &Bs[(wave * 32 + i * 8) * 64]);
    }
    __syncthreads();

#pragma unroll
    for (int ks = 0; ks < 2; ++ks) {
      v8bf af[4], bf[4];
#pragma unroll
      for (int i = 0; i < 4; ++i)
        af[i] = *(const v8bf*)&As[(wm + i * 16 + l16) * 64 + ((ks * 4 + quad) ^ (l16 & 7)) * 8];
#pragma unroll
      for (int j = 0; j < 4; ++j)
        bf[j] = *(const v8bf*)&Bs[(wn + j * 16 + l16) * 64 + ((ks * 4 + quad) ^ (l16 & 7)) * 8];
#pragma unroll
      for (int i = 0; i < 4; ++i)
#pragma unroll
        for (int j = 0; j < 4; ++j)
          acc[i][j] = __builtin_amdgcn_mfma_f32_16x16x32_bf16(af[i], bf[j], acc[i][j], 0, 0, 0);
    }
    __syncthreads();
  }

  if (z < 2) {
    // scatter to [B, H, S, DK] bf16
#pragma unroll
    for (int j = 0; j < 4; ++j) {
      int colg = n0 + wn + j * 16 + l16;
      float bj = bias[colg];
      int h = colg >> 6, d = colg & 63;
#pragma unroll
      for (int i = 0; i < 4; ++i) {
#pragma unroll
        for (int reg = 0; reg < 4; ++reg) {
          int mrow = m0 + wm + i * 16 + quad * 4 + reg;
          int bb = mrow >> 11, ss = mrow & 2047;
          float val = (acc[i][j][reg] + bj) * scale;
          Out[(((size_t)bb * NH + h) * SEQ + ss) * DK + d] = f2bf(val);
        }
      }
    }
  } else {
    // V transposed: [B, H, DK, SEQ]; 4 C-regs = 4 consecutive seq rows
#pragma unroll
    for (int j = 0; j < 4; ++j) {
      int colg = n0 + wn + j * 16 + l16;
      float bj = bias[colg];
      int h = colg >> 6, d = colg & 63;
#pragma unroll
      for (int i = 0; i < 4; ++i) {
        int mrow = m0 + wm + i * 16 + quad * 4;     // 4-aligned
        int bb = mrow >> 11, ss = mrow & 2047;
        uint2 pk = { pack_bf2(acc[i][j][0] + bj, acc[i][j][1] + bj),
                     pack_bf2(acc[i][j][2] + bj, acc[i][j][3] + bj) };
        *(uint2*)(Out + (((size_t)bb * NH + h) * DK + d) * SEQ + ss) = pk;
      }
    }
  }
}

// ---------------------------------------------------------------------------
// Causal flash attention. Block = 128 q-rows x one (b,h). 4 waves; wave w owns
// 32 q-rows. KV chunks of 64, double-buffered LDS via global_load_lds.
// No-max softmax; denominator deferred to epilogue. LDS 40960 B -> 4 blk/CU.
// qt map balances stride-4 residue classes (68 chunks/CU).
// T5 setprio around MFMA clusters (R5: +3%, kept).
// R6: V fragments reg-cached once per chunk (vf depends on (ks,df) only;
//     was re-read per rf -> halves PV LDS reads, 16->8 b128/wave/chunk).
//     +32 VGPR is free: LDS caps occupancy at 4 blocks/CU = 4 waves/SIMD,
//     which tolerates up to 128 VGPRs.
// ---------------------------------------------------------------------------
__global__ __launch_bounds__(256, 2)
void attn_kernel(const unsigned short* __restrict__ Qp,
                 const unsigned short* __restrict__ Kp,
                 const unsigned short* __restrict__ VTp,
                 unsigned short* __restrict__ Xout)
{
  const int y  = blockIdx.y;        // 0..15
  const int r  = y & 3, jj = y >> 2;
  const int qt = (jj == 0) ? (15 - r) : (jj == 1) ? (8 + r) : (jj == 2) ? (7 - r) : r;
  const int bh = blockIdx.x;        // 0..63
  const int b  = bh >> 4, h = bh & 15;

  const unsigned short* Qb = Qp  + ((size_t)bh * SEQ + qt * 128) * DK;
  const unsigned short* Kb = Kp  + (size_t)bh * SEQ * DK;
  const unsigned short* Vb = VTp + (size_t)bh * DK * SEQ;   // [DK][SEQ]

  __shared__ unsigned short Ks[2][64 * 64];   // [kv][d], xor-swizzled 16B cols
  __shared__ unsigned short VTs[2][64 * 64];  // [d][kv], xor-swizzled
  __shared__ unsigned short Ps[4][16 * 64];   // per-wave P, group-swizzled

  const int tid  = threadIdx.x;
  const int lane = tid & 63, wave = tid >> 6;
  const int quad = lane >> 4, l16 = lane & 15;
  const int row_lo = qt * 128 + wave * 32;    // this wave's first q row

  // Q fragments straight from global (A-layout: m=l16, k=quad*8+j)
  v8bf qf[2][2];
#pragma unroll
  for (int rf = 0; rf < 2; ++rf)
#pragma unroll
    for (int ks = 0; ks < 2; ++ks)
      qf[rf][ks] = *(const v8bf*)(Qb + (size_t)(wave * 32 + rf * 16 + l16) * DK + ks * 32 + quad * 8);

  float lp[2][4];                   // per-lane partial row sums (denominator)
  f32x4 o[2][4];
#pragma unroll
  for (int rf = 0; rf < 2; ++rf)
#pragma unroll
    for (int reg = 0; reg < 4; ++reg) lp[rf][reg] = 0.f;
#pragma unroll
  for (int rf = 0; rf < 2; ++rf)
#pragma unroll
    for (int df = 0; df < 4; ++df) o[rf][df] = (f32x4){0.f, 0.f, 0.f, 0.f};

  const int nchunk = 2 * (qt + 1);
  const int lrow = lane >> 3;       // 0..7
  const int lcol = lane & 7;        // physical 16B col within row

  // stage chunk 0 into buf 0
#pragma unroll
  for (int is = 0; is < 2; ++is) {
    int row = wave * 16 + is * 8 + lrow;
    int cK = ((lcol ^ (row & 7)) * 8);
    async_load16(Kb + (size_t)row * DK + cK, &Ks[0][(wave * 16 + is * 8) * 64]);
    async_load16(Vb + (size_t)row * SEQ + cK, &VTs[0][(wave * 16 + is * 8) * 64]);
  }
  __syncthreads();

  for (int c = 0; c < nchunk; ++c) {
    const int buf = c & 1;
    const int kb  = c * 64;

    if (c + 1 < nchunk) {
      const int kb2 = kb + 64;
#pragma unroll
      for (int is = 0; is < 2; ++is) {
        int row = wave * 16 + is * 8 + lrow;
        int cc = ((lcol ^ (row & 7)) * 8);
        async_load16(Kb + (size_t)(kb2 + row) * DK + cc, &Ks[buf ^ 1][(wave * 16 + is * 8) * 64]);
        async_load16(Vb + (size_t)row * SEQ + kb2 + cc, &VTs[buf ^ 1][(wave * 16 + is * 8) * 64]);
      }
    }

    if (kb <= row_lo + 31) {    // wave has unmasked work in this chunk
      // ---- V fragments for this chunk, loaded ONCE (reused by both rf) ----
      v8bf vfr[2][4];
#pragma unroll
      for (int ks = 0; ks < 2; ++ks)
#pragma unroll
        for (int df = 0; df < 4; ++df)
          vfr[ks][df] = *(const v8bf*)&VTs[buf][(df * 16 + l16) * 64 + ((ks * 4 + quad) ^ (l16 & 7)) * 8];

      // ---- S = Q K^T ----
      f32x4 s[2][4];
#pragma unroll
      for (int rf = 0; rf < 2; ++rf)
#pragma unroll
        for (int nf = 0; nf < 4; ++nf) s[rf][nf] = (f32x4){0.f, 0.f, 0.f, 0.f};
      __builtin_amdgcn_s_setprio(1);
#pragma unroll
      for (int ks = 0; ks < 2; ++ks)
#pragma unroll
        for (int nf = 0; nf < 4; ++nf) {
          v8bf kf = *(const v8bf*)&Ks[buf][(nf * 16 + l16) * 64 + ((ks * 4 + quad) ^ (l16 & 7)) * 8];
          s[0][nf] = __builtin_amdgcn_mfma_f32_16x16x32_bf16(qf[0][ks], kf, s[0][nf], 0, 0, 0);
          s[1][nf] = __builtin_amdgcn_mfma_f32_16x16x32_bf16(qf[1][ks], kf, s[1][nf], 0, 0, 0);
        }
      __builtin_amdgcn_s_setprio(0);

      // ---- causal mask (only on diagonal-touching chunks) ----
      if (kb + 63 > row_lo) {
#pragma unroll
        for (int rf = 0; rf < 2; ++rf)
#pragma unroll
          for (int nf = 0; nf < 4; ++nf) {
            int col = kb + nf * 16 + l16;
#pragma unroll
            for (int reg = 0; reg < 4; ++reg)
              if (col > row_lo + rf * 16 + quad * 4 + reg) s[rf][nf][reg] = -1e30f;
          }
      }

      // ---- exp2 (no max subtraction) + deferred denominator + PV ----
#pragma unroll
      for (int rf = 0; rf < 2; ++rf) {
#pragma unroll
        for (int nf = 0; nf < 4; ++nf)
#pragma unroll
          for (int reg = 0; reg < 4; ++reg)
            s[rf][nf][reg] = __builtin_amdgcn_exp2f(s[rf][nf][reg]);
#pragma unroll
        for (int reg = 0; reg < 4; ++reg)
          lp[rf][reg] += (s[rf][0][reg] + s[rf][1][reg]) + (s[rf][2][reg] + s[rf][3][reg]);

        // P: C-layout -> per-wave LDS, swizzled: addr = row*64 + ((g ^ quad*2)*8 + off)
#pragma unroll
        for (int nf = 0; nf < 4; ++nf)
#pragma unroll
          for (int reg = 0; reg < 4; ++reg)
            Ps[wave][(quad * 4 + reg) * 64 +
                     (((nf * 2 + (l16 >> 3)) ^ (quad * 2)) * 8) + (l16 & 7)] =
                f2bf(s[rf][nf][reg]);

        // A-frag read: row=l16, k-group ks*4+quad, unswizzle with key (l16>>2)*2
        __builtin_amdgcn_s_setprio(1);
#pragma unroll
        for (int ks = 0; ks < 2; ++ks) {
          v8bf pf = *(const v8bf*)&Ps[wave][l16 * 64 + (((ks * 4 + quad) ^ ((l16 >> 2) * 2)) * 8)];
#pragma unroll
          for (int df = 0; df < 4; ++df)
            o[rf][df] = __builtin_amdgcn_mfma_f32_16x16x32_bf16(pf, vfr[ks][df], o[rf][df], 0, 0, 0);
        }
        __builtin_amdgcn_s_setprio(0);
      }
    }
    __syncthreads();   // drains async loads (buf^1) + protects buf for c+2
  }

  // epilogue: one denominator reduction, then [B, S, H*DK] bf16
#pragma unroll
  for (int rf = 0; rf < 2; ++rf) {
#pragma unroll
    for (int off = 1; off < 16; off <<= 1)
#pragma unroll
      for (int reg = 0; reg < 4; ++reg) lp[rf][reg] += __shfl_xor(lp[rf][reg], off);
    float inv[4];
#pragma unroll
    for (int reg = 0; reg < 4; ++reg) inv[reg] = 1.0f / lp[rf][reg];
#pragma unroll
    for (int df = 0; df < 4; ++df)
#pragma unroll
      for (int reg = 0; reg < 4; ++reg) {
        int qrow = row_lo + rf * 16 + quad * 4 + reg;
        Xout[(size_t)(b * SEQ + qrow) * DMODEL + h * DK + df * 16 + l16] =
            f2bf(o[rf][df][reg] * inv[reg]);
      }
  }
}

// ---------------------------------------------------------------------------
// Output projection (bf16 GEMM, fp32 out): d_out = Xa @ Wo^T + bo
// ---------------------------------------------------------------------------
__global__ __launch_bounds__(256, 2)
void oproj_kernel(const unsigned short* __restrict__ Xa,
                  const unsigned short* __restrict__ Woc,
                  const float* __restrict__ bo,
                  float* __restrict__ Out)
{
  __shared__ unsigned short As[128 * 64];
  __shared__ unsigned short Bs[128 * 64];

  const int tid  = threadIdx.x;
  const int m0   = blockIdx.x * 128;
  const int n0   = blockIdx.y * 128;
  const int lane = tid & 63;
  const int wave = tid >> 6;
  const int quad = lane >> 4;
  const int l16  = lane & 15;
  const int wm   = (wave >> 1) * 64;
  const int wn   = (wave & 1) * 64;
  const int lrow = lane >> 3;
  const int lcol = lane & 7;

  f32x4 acc[4][4];
#pragma unroll
  for (int i = 0; i < 4; ++i)
#pragma unroll
    for (int j = 0; j < 4; ++j) acc[i][j] = (f32x4){0.f, 0.f, 0.f, 0.f};

  for (int k0 = 0; k0 < DMODEL; k0 += 64) {
#pragma unroll
    for (int i = 0; i < 4; ++i) {
      int row = wave * 32 + i * 8 + lrow;
      int gc = (lcol ^ (row & 7)) * 8;
      async_load16(Xa  + (size_t)(m0 + row) * DMODEL + k0 + gc, &As[(wave * 32 + i * 8) * 64]);
      async_load16(Woc + (size_t)(n0 + row) * DMODEL + k0 + gc, &Bs[(wave * 32 + i * 8) * 64]);
    }
    __syncthreads();

#pragma unroll
    for (int ks = 0; ks < 2; ++ks) {
      v8bf af[4], bf[4];
#pragma unroll
      for (int i = 0; i < 4; ++i)
        af[i] = *(const v8bf*)&As[(wm + i * 16 + l16) * 64 + ((ks * 4 + quad) ^ (l16 & 7)) * 8];
#pragma unroll
      for (int j = 0; j < 4; ++j)
        bf[j] = *(const v8bf*)&Bs[(wn + j * 16 + l16) * 64 + ((ks * 4 + quad) ^ (l16 & 7)) * 8];
#pragma unroll
      for (int i = 0; i < 4; ++i)
#pragma unroll
        for (int j = 0; j < 4; ++j)
          acc[i][j] = __builtin_amdgcn_mfma_f32_16x16x32_bf16(af[i], bf[j], acc[i][j], 0, 0, 0);
    }
    __syncthreads();
  }

#pragma unroll
  for (int j = 0; j < 4; ++j) {
    int colg = n0 + wn + j * 16 + l16;
    float bj = bo[colg];
#pragma unroll
    for (int i = 0; i < 4; ++i) {
#pragma unroll
      for (int reg = 0; reg < 4; ++reg) {
        int mrow = m0 + wm + i * 16 + quad * 4 + reg;
        Out[(size_t)mrow * DMODEL + colg] = acc[i][j][reg] + bj;
      }
    }
  }
}

extern "C" void kernel_launch(void* const* d_in, const int* in_sizes, int n_in,
                              void* d_out, int out_size, void* d_ws, size_t ws_size,
                              hipStream_t stream)
{
  const float* query = (const float*)d_in[0];
  const float* key   = (const float*)d_in[1];
  const float* value = (const float*)d_in[2];
  const float* Wq = (const float*)d_in[3];
  const float* bq = (const float*)d_in[4];
  const float* Wk = (const float*)d_in[5];
  const float* bk = (const float*)d_in[6];
  const float* Wv = (const float*)d_in[7];
  const float* bv = (const float*)d_in[8];
  const float* Wo = (const float*)d_in[9];
  const float* bo = (const float*)d_in[10];

  const size_t tsz = (size_t)M_TOT * DMODEL;   // elements per bf16 X-tensor
  const size_t wsz = (size_t)DMODEL * DMODEL;  // elements per bf16 W-tensor
  unsigned short* Qp  = (unsigned short*)d_ws;
  unsigned short* Kp  = Qp + tsz;
  unsigned short* Vp  = Kp + tsz;   // transposed per-head: [B,H,DK,SEQ]
  unsigned short* Xa  = Vp + tsz;
  unsigned short* Xqc = Xa + tsz;
  unsigned short* Xkc = Xqc + tsz;
  unsigned short* Xvc = Xkc + tsz;
  unsigned short* Wqc = Xvc + tsz;
  unsigned short* Wkc = Wqc + wsz;
  unsigned short* Wvc = Wkc + wsz;
  unsigned short* Woc = Wvc + wsz;

  cvt_kernel<<<dim3(1024, 7), 256, 0, stream>>>(query, key, value, Wq, Wk, Wv, Wo,
                                                Xqc, Xkc, Xvc, Wqc, Wkc, Wvc, Woc);
  proj_bf16_kernel<<<dim3(64, 8, 3), 256, 0, stream>>>(Xqc, Xkc, Xvc, Wqc, Wkc, Wvc,
                                                       bq, bk, bv, Qp, Kp, Vp);
  attn_kernel<<<dim3(64, 16), 256, 0, stream>>>(Qp, Kp, Vp, Xa);
  oproj_kernel<<<dim3(64, 8), 256, 0, stream>>>(Xa, Woc, bo, (float*)d_out);
}